// Round 1
// baseline (12506.033 us; speedup 1.0000x reference)
//
#include <hip/hip_runtime.h>
#include <hip/hip_bf16.h>

#define NN 50000
#define EE 1000000
#define NGRAPHS 64
#define OUTD 100

#define INV_SQRT_NEIGH 0.22360679774997896f   // 1/sqrt(20)
#define INV_SQRT_NODES 0.035777087639996634f  // 1/sqrt(781.25)
#define SQRT3 1.7320508075688772f
#define BSCALE 2.8234621879136734f            // sqrt(10)/1.12
#define BSTEP 0.3888888888888889f             // 3.5/9
#define INV_BSTEP 2.5714285714285716f
#define PI_F 3.14159265358979323846f

__device__ __forceinline__ float silu_f(float x) { return x / (1.0f + __expf(-x)); }
__device__ __forceinline__ float sigm_f(float x) { return 1.0f / (1.0f + __expf(-x)); }

// ---- per-edge geometry: cutoff*Y0, cutoff*Y1, gaussian basis ----
__device__ __forceinline__ void edge_features(
    int e, const float* __restrict__ pos, const int* __restrict__ ei,
    const float* __restrict__ eshift, const float* __restrict__ lat,
    const int* __restrict__ batch,
    int& src, int& dst, float& cs0, float* csh1, float* b)
{
    src = ei[e];
    dst = ei[EE + e];
    int g = batch[src];
    const float* L = lat + g * 9;
    float t0 = eshift[e*3+0], t1 = eshift[e*3+1], t2 = eshift[e*3+2];
    float vx = pos[dst*3+0] - pos[src*3+0] + t0*L[0] + t1*L[3] + t2*L[6];
    float vy = pos[dst*3+1] - pos[src*3+1] + t0*L[1] + t1*L[4] + t2*L[7];
    float vz = pos[dst*3+2] - pos[src*3+2] + t0*L[2] + t1*L[5] + t2*L[8];
    float r = sqrtf(vx*vx + vy*vy + vz*vz);
    float u = 2.0f * (r * (1.0f/3.5f) - 1.0f);
    float cut;
    if (u > 0.0f) cut = 0.0f;
    else if (u < -2.0f) cut = 1.0f;
    else cut = 0.5f * (1.0f - __cosf(PI_F * u));
    cs0 = cut;
    float inv = 1.0f / fmaxf(r, 1e-12f);
    float sc = SQRT3 * cut * inv;
    csh1[0] = sc * vx; csh1[1] = sc * vy; csh1[2] = sc * vz;
#pragma unroll
    for (int i = 0; i < 10; ++i) {
        float d = (r - (float)i * BSTEP) * INV_BSTEP;
        b[i] = __expf(-d * d) * BSCALE;
    }
}

// ---- prep: transpose small weights for contiguous row reads ----
__global__ __launch_bounds__(256) void k_prep(
    const float* __restrict__ fc1w0, const float* __restrict__ fc2w0,
    const float* __restrict__ fcow0, const float* __restrict__ fc2w1,
    float* __restrict__ t10, float* __restrict__ t20,
    float* __restrict__ to0, float* __restrict__ t21)
{
    int idx = blockIdx.x * 256 + threadIdx.x;
    if (idx < 1000) {                    // (10,100) -> (100,10)
        int j = idx / 10, i = idx % 10;
        t10[idx] = fc1w0[i * 100 + j];
    } else if (idx < 2000) {
        int t = idx - 1000; int j = t / 10, i = t % 10;
        t20[t] = fc2w0[i * 100 + j];
    } else if (idx < 3000) {
        int t = idx - 2000; int j = t / 10, i = t % 10;
        to0[t] = fcow0[i * 100 + j];
    } else if (idx < 19000) {            // (100,160) -> (160,100)
        int t = idx - 3000; int k = t / 100, j = t % 100;
        t21[t] = fc2w1[j * 160 + k];
    }
}

// ---- layer 1 edge kernel: 16x0e -> messages (16x0e, 16x1o) ----
__global__ __launch_bounds__(256) void k_edge1(
    const float* __restrict__ pos, const float* __restrict__ x,
    const int* __restrict__ ei, const float* __restrict__ eshift,
    const float* __restrict__ lat, const int* __restrict__ batch,
    const float* __restrict__ tw0,   // (100,10)
    const float* __restrict__ w1,    // (100,32)
    float* __restrict__ a1s, float* __restrict__ a1v)
{
    int e = blockIdx.x * 256 + threadIdx.x;
    if (e >= EE) return;
    int src, dst; float cs0, csh1[3], b[10];
    edge_features(e, pos, ei, eshift, lat, batch, src, dst, cs0, csh1, b);

    float wk[32];
#pragma unroll
    for (int k = 0; k < 32; ++k) wk[k] = 0.0f;
    for (int j = 0; j < 100; ++j) {
        float t = 0.0f;
#pragma unroll
        for (int i = 0; i < 10; ++i) t += b[i] * tw0[j * 10 + i];
        float hj = silu_f(t);
#pragma unroll
        for (int k = 0; k < 32; ++k) wk[k] += hj * w1[j * 32 + k];
    }
    const float* xp = x + src * 16;
    float* asp = a1s + dst * 16;
    float* avp = a1v + dst * 48;   // (N,3,16)
#pragma unroll
    for (int k = 0; k < 16; ++k) {
        float xs = xp[k];
        unsafeAtomicAdd(asp + k, wk[k] * xs * cs0);
        float mv = wk[16 + k] * xs;
        unsafeAtomicAdd(avp + k,        mv * csh1[0]);
        unsafeAtomicAdd(avp + 16 + k,   mv * csh1[1]);
        unsafeAtomicAdd(avp + 32 + k,   mv * csh1[2]);
    }
}

// ---- layer 1 node update ----
__global__ __launch_bounds__(256) void k_node1(
    const float* __restrict__ x, const float* __restrict__ z,
    const float* __restrict__ a1s, const float* __restrict__ a1v,
    const float* __restrict__ sc1, const float* __restrict__ lin1s,
    const float* __restrict__ lin1v,
    float* __restrict__ s1, float* __restrict__ v1)
{
    int n = blockIdx.x * 256 + threadIdx.x;
    if (n >= NN) return;
    float zz = z[n];
    float xs[16], as[16];
#pragma unroll
    for (int c = 0; c < 16; ++c) {
        xs[c] = x[n * 16 + c] * zz;
        as[c] = a1s[n * 16 + c] * INV_SQRT_NEIGH;
    }
    float sh[64];
#pragma unroll
    for (int o = 0; o < 64; ++o) sh[o] = 0.0f;
    for (int c = 0; c < 16; ++c) {
        float xc = xs[c], ac = as[c];
#pragma unroll
        for (int o = 0; o < 64; ++o)
            sh[o] += xc * sc1[c * 64 + o] + ac * lin1s[c * 64 + o];
    }
    float gate[32];
#pragma unroll
    for (int o = 0; o < 32; ++o) {
        s1[n * 32 + o] = silu_f(sh[o]);
        gate[o] = sigm_f(sh[32 + o]);
    }
    for (int i = 0; i < 3; ++i) {
        float av[16];
#pragma unroll
        for (int c = 0; c < 16; ++c) av[c] = a1v[n * 48 + i * 16 + c] * INV_SQRT_NEIGH;
        float vh[32];
#pragma unroll
        for (int o = 0; o < 32; ++o) vh[o] = 0.0f;
        for (int c = 0; c < 16; ++c) {
            float ac = av[c];
#pragma unroll
            for (int o = 0; o < 32; ++o) vh[o] += ac * lin1v[c * 32 + o];
        }
#pragma unroll
        for (int o = 0; o < 32; ++o) v1[(n * 3 + i) * 32 + o] = vh[o] * gate[o];
    }
}

// ---- layer 2 edge kernel ----
__global__ __launch_bounds__(256) void k_edge2(
    const float* __restrict__ pos, const int* __restrict__ ei,
    const float* __restrict__ eshift, const float* __restrict__ lat,
    const int* __restrict__ batch,
    const float* __restrict__ tw0,   // (100,10)
    const float* __restrict__ tW,    // (160,100)
    const float* __restrict__ s1, const float* __restrict__ v1,
    float* __restrict__ a2s, float* __restrict__ a2v)
{
    int e = blockIdx.x * 256 + threadIdx.x;
    if (e >= EE) return;
    int src, dst; float cs0, csh1[3], b[10];
    edge_features(e, pos, ei, eshift, lat, batch, src, dst, cs0, csh1, b);

    float h[100];
#pragma unroll
    for (int j = 0; j < 100; ++j) {
        float t = 0.0f;
#pragma unroll
        for (int i = 0; i < 10; ++i) t += b[i] * tw0[j * 10 + i];
        h[j] = silu_f(t);
    }
    const float* sp = s1 + src * 32;
    const float* vp = v1 + src * 96;   // (3,32)
    float* asp = a2s + dst * 32;
    float* avp = a2v + dst * 96;       // (N,3,32)
    for (int c = 0; c < 32; ++c) {
        float w1a = 0, w2a = 0, w3a = 0, w4a = 0, w5a = 0;
        const float* r1 = tW + c * 100;
        const float* r2 = tW + (32 + c) * 100;
        const float* r3 = tW + (64 + c) * 100;
        const float* r4 = tW + (96 + c) * 100;
        const float* r5 = tW + (128 + c) * 100;
#pragma unroll
        for (int j = 0; j < 100; ++j) {
            float hj = h[j];
            w1a += hj * r1[j];
            w2a += hj * r2[j];
            w3a += hj * r3[j];
            w4a += hj * r4[j];
            w5a += hj * r5[j];
        }
        float ssc = sp[c];
        float vx = vp[c], vy = vp[32 + c], vz = vp[64 + c];
        float dotv = vx * csh1[0] + vy * csh1[1] + vz * csh1[2];
        unsafeAtomicAdd(asp + c, w1a * ssc * cs0 + w2a * dotv);
        float cx = vy * csh1[2] - vz * csh1[1];
        float cy = vz * csh1[0] - vx * csh1[2];
        float cz = vx * csh1[1] - vy * csh1[0];
        unsafeAtomicAdd(avp + c,      w3a * ssc * csh1[0] + w4a * vx * cs0 + w5a * cx);
        unsafeAtomicAdd(avp + 32 + c, w3a * ssc * csh1[1] + w4a * vy * cs0 + w5a * cy);
        unsafeAtomicAdd(avp + 64 + c, w3a * ssc * csh1[2] + w4a * vz * cs0 + w5a * cz);
    }
}

// ---- layer 2 node update ----
__global__ __launch_bounds__(256) void k_node2(
    const float* __restrict__ z,
    const float* __restrict__ s1, const float* __restrict__ v1,
    const float* __restrict__ a2s, const float* __restrict__ a2v,
    const float* __restrict__ sc2s, const float* __restrict__ sc2v,
    const float* __restrict__ lin2s, const float* __restrict__ lin2v,
    float* __restrict__ s2, float* __restrict__ v2)
{
    int n = blockIdx.x * 256 + threadIdx.x;
    if (n >= NN) return;
    float zz = z[n];
    float sv[32], as[32];
#pragma unroll
    for (int c = 0; c < 32; ++c) {
        sv[c] = s1[n * 32 + c] * zz;
        as[c] = a2s[n * 32 + c] * INV_SQRT_NEIGH;
    }
    float sh[64];
#pragma unroll
    for (int o = 0; o < 64; ++o) sh[o] = 0.0f;
    for (int c = 0; c < 32; ++c) {
        float a = sv[c], d = as[c];
#pragma unroll
        for (int o = 0; o < 64; ++o)
            sh[o] += a * sc2s[c * 64 + o] + d * lin2s[c * 64 + o];
    }
    float gate[32];
#pragma unroll
    for (int o = 0; o < 32; ++o) {
        s2[n * 32 + o] = silu_f(sh[o]);
        gate[o] = sigm_f(sh[32 + o]);
    }
    for (int i = 0; i < 3; ++i) {
        float vv[32], av[32];
#pragma unroll
        for (int c = 0; c < 32; ++c) {
            vv[c] = v1[(n * 3 + i) * 32 + c];
            av[c] = a2v[n * 96 + i * 32 + c] * INV_SQRT_NEIGH;
        }
        float vh[32];
#pragma unroll
        for (int o = 0; o < 32; ++o) vh[o] = 0.0f;
        for (int c = 0; c < 32; ++c) {
            float a = vv[c], d = av[c];
#pragma unroll
            for (int o = 0; o < 32; ++o)
                vh[o] += a * sc2v[c * 32 + o] + d * lin2v[c * 32 + o];
        }
#pragma unroll
        for (int o = 0; o < 32; ++o) v2[(n * 3 + i) * 32 + o] = vh[o] * gate[o];
    }
}

// ---- output conv edge kernel ----
__global__ __launch_bounds__(256) void k_edge3(
    const float* __restrict__ pos, const int* __restrict__ ei,
    const float* __restrict__ eshift, const float* __restrict__ lat,
    const int* __restrict__ batch,
    const float* __restrict__ tw0,   // (100,10)
    const float* __restrict__ w1,    // (100,64)
    const float* __restrict__ s2, const float* __restrict__ v2,
    float* __restrict__ a3)
{
    int e = blockIdx.x * 256 + threadIdx.x;
    if (e >= EE) return;
    int src, dst; float cs0, csh1[3], b[10];
    edge_features(e, pos, ei, eshift, lat, batch, src, dst, cs0, csh1, b);

    float wk[64];
#pragma unroll
    for (int k = 0; k < 64; ++k) wk[k] = 0.0f;
    for (int j = 0; j < 100; ++j) {
        float t = 0.0f;
#pragma unroll
        for (int i = 0; i < 10; ++i) t += b[i] * tw0[j * 10 + i];
        float hj = silu_f(t);
#pragma unroll
        for (int k = 0; k < 64; ++k) wk[k] += hj * w1[j * 64 + k];
    }
    const float* sp = s2 + src * 32;
    const float* vp = v2 + src * 96;
    float* ap = a3 + dst * 32;
#pragma unroll
    for (int c = 0; c < 32; ++c) {
        float dotv = vp[c] * csh1[0] + vp[32 + c] * csh1[1] + vp[64 + c] * csh1[2];
        unsafeAtomicAdd(ap + c, wk[c] * sp[c] * cs0 + wk[32 + c] * dotv);
    }
}

// ---- output node + graph reduce ----
__global__ __launch_bounds__(256) void k_nodeout(
    const float* __restrict__ z, const int* __restrict__ batch,
    const float* __restrict__ s2, const float* __restrict__ a3,
    const float* __restrict__ sco, const float* __restrict__ lino,
    float* __restrict__ out)
{
    int n = blockIdx.x * 256 + threadIdx.x;
    if (n >= NN) return;
    int g = batch[n];
    float zz = z[n];
    float sv[32], av[32];
#pragma unroll
    for (int c = 0; c < 32; ++c) {
        sv[c] = s2[n * 32 + c] * zz;
        av[c] = a3[n * 32 + c] * INV_SQRT_NEIGH;
    }
    for (int half = 0; half < 2; ++half) {
        float acc[50];
#pragma unroll
        for (int o = 0; o < 50; ++o) acc[o] = 0.0f;
        for (int c = 0; c < 32; ++c) {
            float a = sv[c], d = av[c];
            const float* srow = sco + c * 100 + half * 50;
            const float* lrow = lino + c * 100 + half * 50;
#pragma unroll
            for (int o = 0; o < 50; ++o) acc[o] += a * srow[o] + d * lrow[o];
        }
#pragma unroll
        for (int o = 0; o < 50; ++o)
            unsafeAtomicAdd(out + g * 100 + half * 50 + o, acc[o] * INV_SQRT_NODES);
    }
}

extern "C" void kernel_launch(void* const* d_in, const int* in_sizes, int n_in,
                              void* d_out, int out_size, void* d_ws, size_t ws_size,
                              hipStream_t stream)
{
    const float* pos   = (const float*)d_in[0];
    const float* x     = (const float*)d_in[1];
    const float* z     = (const float*)d_in[2];
    const int*   ei    = (const int*)d_in[3];
    const float* esh   = (const float*)d_in[4];
    const float* lat   = (const float*)d_in[5];
    const int*   batch = (const int*)d_in[6];
    const float* fc1w0 = (const float*)d_in[7];
    const float* fc1w1 = (const float*)d_in[8];
    const float* sc1   = (const float*)d_in[9];
    const float* lin1s = (const float*)d_in[10];
    const float* lin1v = (const float*)d_in[11];
    const float* fc2w0 = (const float*)d_in[12];
    const float* fc2w1 = (const float*)d_in[13];
    const float* sc2s  = (const float*)d_in[14];
    const float* sc2v  = (const float*)d_in[15];
    const float* lin2s = (const float*)d_in[16];
    const float* lin2v = (const float*)d_in[17];
    const float* fcow0 = (const float*)d_in[18];
    const float* fcow1 = (const float*)d_in[19];
    const float* sco   = (const float*)d_in[20];
    const float* lino  = (const float*)d_in[21];
    float* out = (float*)d_out;

    float* p = (float*)d_ws;
    float* a1s = p; p += NN * 16;
    float* a1v = p; p += NN * 48;
    float* a2s = p; p += NN * 32;
    float* a2v = p; p += NN * 96;
    float* a3  = p; p += NN * 32;   // accumulators: NN*224 floats total
    float* s1  = p; p += NN * 32;
    float* v1  = p; p += NN * 96;
    float* s2  = p; p += NN * 32;
    float* v2  = p; p += NN * 96;
    float* t10 = p; p += 1000;
    float* t20 = p; p += 1000;
    float* to0 = p; p += 1000;
    float* t21 = p; p += 16000;

    hipMemsetAsync(d_ws, 0, (size_t)NN * 224 * sizeof(float), stream);
    hipMemsetAsync(d_out, 0, (size_t)out_size * sizeof(float), stream);

    k_prep<<<75, 256, 0, stream>>>(fc1w0, fc2w0, fcow0, fc2w1, t10, t20, to0, t21);

    int eb = (EE + 255) / 256;
    int nb = (NN + 255) / 256;
    k_edge1<<<eb, 256, 0, stream>>>(pos, x, ei, esh, lat, batch, t10, fc1w1, a1s, a1v);
    k_node1<<<nb, 256, 0, stream>>>(x, z, a1s, a1v, sc1, lin1s, lin1v, s1, v1);
    k_edge2<<<eb, 256, 0, stream>>>(pos, ei, esh, lat, batch, t20, t21, s1, v1, a2s, a2v);
    k_node2<<<nb, 256, 0, stream>>>(z, s1, v1, a2s, a2v, sc2s, sc2v, lin2s, lin2v, s2, v2);
    k_edge3<<<eb, 256, 0, stream>>>(pos, ei, esh, lat, batch, to0, fcow1, s2, v2, a3);
    k_nodeout<<<nb, 256, 0, stream>>>(z, batch, s2, a3, sco, lino, out);
}

// Round 2
// 12002.976 us; speedup vs baseline: 1.0419x; 1.0419x over previous
//
#include <hip/hip_runtime.h>
#include <hip/hip_bf16.h>

#define NN 50000
#define EE 1000000
#define NGRAPHS 64
#define OUTD 100
#define NB_N 196        // (NN+255)/256
#define NB_E 3907       // (EE+255)/256

#define INV_SQRT_NEIGH 0.22360679774997896f   // 1/sqrt(20)
#define INV_SQRT_NODES 0.035777087639996634f  // 1/sqrt(781.25)
#define SQRT3 1.7320508075688772f
#define BSCALE 2.8234621879136734f            // sqrt(10)/1.12
#define BSTEP 0.3888888888888889f             // 3.5/9
#define INV_BSTEP 2.5714285714285716f
#define PI_F 3.14159265358979323846f

__device__ __forceinline__ float silu_f(float x) { return x / (1.0f + __expf(-x)); }
__device__ __forceinline__ float sigm_f(float x) { return 1.0f / (1.0f + __expf(-x)); }

// pack two fp32 -> bf16 pair (RTNE) in one uint
__device__ __forceinline__ unsigned pk(float a, float b) {
    union { float f; unsigned u; } ua, ub; ua.f = a; ub.f = b;
    unsigned x = ua.u + 0x7fffu + ((ua.u >> 16) & 1u);
    unsigned y = ub.u + 0x7fffu + ((ub.u >> 16) & 1u);
    return (x >> 16) | (y & 0xffff0000u);
}

// ---- per-edge geometry: cutoff*Y0, cutoff*Y1, gaussian basis ----
__device__ __forceinline__ void edge_features(
    int e, const float* __restrict__ pos, const int* __restrict__ ei,
    const float* __restrict__ eshift, const float* __restrict__ lat,
    const int* __restrict__ batch,
    int& src, int& dst, float& cs0, float* csh1, float* b)
{
    src = ei[e];
    dst = ei[EE + e];
    int g = batch[src];
    const float* L = lat + g * 9;
    float t0 = eshift[e*3+0], t1 = eshift[e*3+1], t2 = eshift[e*3+2];
    float vx = pos[dst*3+0] - pos[src*3+0] + t0*L[0] + t1*L[3] + t2*L[6];
    float vy = pos[dst*3+1] - pos[src*3+1] + t0*L[1] + t1*L[4] + t2*L[7];
    float vz = pos[dst*3+2] - pos[src*3+2] + t0*L[2] + t1*L[5] + t2*L[8];
    float r = sqrtf(vx*vx + vy*vy + vz*vz);
    float u = 2.0f * (r * (1.0f/3.5f) - 1.0f);
    float cut;
    if (u > 0.0f) cut = 0.0f;
    else if (u < -2.0f) cut = 1.0f;
    else cut = 0.5f * (1.0f - __cosf(PI_F * u));
    cs0 = cut;
    float inv = 1.0f / fmaxf(r, 1e-12f);
    float sc = SQRT3 * cut * inv;
    csh1[0] = sc * vx; csh1[1] = sc * vy; csh1[2] = sc * vz;
#pragma unroll
    for (int i = 0; i < 10; ++i) {
        float d = (r - (float)i * BSTEP) * INV_BSTEP;
        b[i] = __expf(-d * d) * BSCALE;
    }
}

// ---- prep: transpose small weights for contiguous row reads ----
__global__ __launch_bounds__(256) void k_prep(
    const float* __restrict__ fc1w0, const float* __restrict__ fc2w0,
    const float* __restrict__ fcow0, const float* __restrict__ fc2w1,
    float* __restrict__ t10, float* __restrict__ t20,
    float* __restrict__ to0, float* __restrict__ t21)
{
    int idx = blockIdx.x * 256 + threadIdx.x;
    if (idx < 1000) {                    // (10,100) -> (100,10)
        int j = idx / 10, i = idx % 10;
        t10[idx] = fc1w0[i * 100 + j];
    } else if (idx < 2000) {
        int t = idx - 1000; int j = t / 10, i = t % 10;
        t20[t] = fc2w0[i * 100 + j];
    } else if (idx < 3000) {
        int t = idx - 2000; int j = t / 10, i = t % 10;
        to0[t] = fcow0[i * 100 + j];
    } else if (idx < 19000) {            // (100,160) -> (160,100)
        int t = idx - 3000; int k = t / 100, j = t % 100;
        t21[t] = fc2w1[j * 160 + k];
    }
}

// ================= CSR build =================
__global__ __launch_bounds__(256) void k_hist(const int* __restrict__ ei, int* __restrict__ deg)
{
    int e = blockIdx.x * 256 + threadIdx.x;
    if (e < EE) atomicAdd(&deg[ei[EE + e]], 1);
}

__global__ __launch_bounds__(256) void k_scan1(const int* __restrict__ deg, int* __restrict__ bsum)
{
    __shared__ int sd[256];
    int t = threadIdx.x;
    int i = blockIdx.x * 256 + t;
    sd[t] = (i < NN) ? deg[i] : 0;
    __syncthreads();
#pragma unroll
    for (int o = 128; o > 0; o >>= 1) {
        if (t < o) sd[t] += sd[t + o];
        __syncthreads();
    }
    if (t == 0) bsum[blockIdx.x] = sd[0];
}

__global__ void k_scan2(const int* __restrict__ bsum, int* __restrict__ boff, int* __restrict__ rowp)
{
    if (threadIdx.x == 0) {
        int acc = 0;
        for (int b = 0; b < NB_N; ++b) { boff[b] = acc; acc += bsum[b]; }
        rowp[NN] = EE;
    }
}

__global__ __launch_bounds__(256) void k_scan3(
    const int* __restrict__ deg, const int* __restrict__ boff,
    int* __restrict__ rowp, int* __restrict__ cursor)
{
    __shared__ int sd[256];
    int t = threadIdx.x;
    int i = blockIdx.x * 256 + t;
    int v = (i < NN) ? deg[i] : 0;
    sd[t] = v;
    __syncthreads();
#pragma unroll
    for (int o = 1; o < 256; o <<= 1) {
        int xv = 0;
        if (t >= o) xv = sd[t - o];
        __syncthreads();
        sd[t] += xv;
        __syncthreads();
    }
    if (i < NN) {
        int val = boff[blockIdx.x] + sd[t] - v;   // exclusive
        rowp[i] = val;
        cursor[i] = val;
    }
}

// compute edge geometry once, scatter to dst-sorted slot (64B record)
__global__ __launch_bounds__(256) void k_geom(
    const float* __restrict__ pos, const int* __restrict__ ei,
    const float* __restrict__ eshift, const float* __restrict__ lat,
    const int* __restrict__ batch, int* __restrict__ cursor,
    float4* __restrict__ geo)
{
    int e = blockIdx.x * 256 + threadIdx.x;
    if (e >= EE) return;
    int src, dst; float cs0, csh[3], b[10];
    edge_features(e, pos, ei, eshift, lat, batch, src, dst, cs0, csh, b);
    int slot = atomicAdd(&cursor[dst], 1);
    float4* gp = geo + (size_t)slot * 4;
    gp[0] = make_float4(cs0, csh[0], csh[1], csh[2]);
    gp[1] = make_float4(b[0], b[1], b[2], b[3]);
    gp[2] = make_float4(b[4], b[5], b[6], b[7]);
    gp[3] = make_float4(b[8], b[9], __int_as_float(src), 0.0f);
}

// graph boundaries from sorted batch
__global__ __launch_bounds__(256) void k_gb(const int* __restrict__ batch, int* __restrict__ gstart)
{
    int n = blockIdx.x * 256 + threadIdx.x;
    if (n >= NN) return;
    int b = batch[n];
    if (n == 0) { for (int g = 0; g <= b; ++g) gstart[g] = 0; }
    else {
        int pb = batch[n - 1];
        for (int g = pb + 1; g <= b; ++g) gstart[g] = n;
    }
    if (n == NN - 1) { for (int g = b + 1; g <= NGRAPHS; ++g) gstart[g] = NN; }
}

// ================= sorted edge kernels (write bf16 msgs, no atomics) =================
__global__ __launch_bounds__(256) void k_edge1s(
    const float4* __restrict__ geo, const float* __restrict__ x,
    const float* __restrict__ tw0, const float* __restrict__ w1,
    unsigned* __restrict__ msg)
{
    int s = blockIdx.x * 256 + threadIdx.x;
    if (s >= EE) return;
    float4 g0 = geo[(size_t)s*4+0], g1 = geo[(size_t)s*4+1], g2 = geo[(size_t)s*4+2], g3 = geo[(size_t)s*4+3];
    float cs0 = g0.x, c1 = g0.y, c2 = g0.z, c3 = g0.w;
    float b[10] = {g1.x,g1.y,g1.z,g1.w,g2.x,g2.y,g2.z,g2.w,g3.x,g3.y};
    int src = __float_as_int(g3.z);

    float wk[32];
#pragma unroll
    for (int k = 0; k < 32; ++k) wk[k] = 0.0f;
    for (int j = 0; j < 100; ++j) {
        float t = 0.0f;
#pragma unroll
        for (int i = 0; i < 10; ++i) t += b[i] * tw0[j * 10 + i];
        float hj = silu_f(t);
#pragma unroll
        for (int k = 0; k < 32; ++k) wk[k] += hj * w1[j * 32 + k];
    }
    const float* xp = x + src * 16;
    unsigned* mp = msg + (size_t)s * 32;
#pragma unroll
    for (int c = 0; c < 16; c += 2) {
        float x0 = xp[c], x1 = xp[c+1];
        float ms0 = wk[c] * x0 * cs0,   ms1 = wk[c+1] * x1 * cs0;
        float m0  = wk[16+c] * x0,      m1  = wk[17+c] * x1;
        mp[c/2]      = pk(ms0, ms1);
        mp[8 + c/2]  = pk(m0*c1, m1*c1);
        mp[16 + c/2] = pk(m0*c2, m1*c2);
        mp[24 + c/2] = pk(m0*c3, m1*c3);
    }
}

__global__ __launch_bounds__(256) void k_edge2s(
    const float4* __restrict__ geo,
    const float* __restrict__ tw0, const float* __restrict__ tW,
    const float* __restrict__ s1, const float* __restrict__ v1,
    unsigned* __restrict__ msg)
{
    int s = blockIdx.x * 256 + threadIdx.x;
    if (s >= EE) return;
    float4 g0 = geo[(size_t)s*4+0], g1 = geo[(size_t)s*4+1], g2 = geo[(size_t)s*4+2], g3 = geo[(size_t)s*4+3];
    float cs0 = g0.x, c1 = g0.y, c2 = g0.z, c3 = g0.w;
    float b[10] = {g1.x,g1.y,g1.z,g1.w,g2.x,g2.y,g2.z,g2.w,g3.x,g3.y};
    int src = __float_as_int(g3.z);

    float h[100];
#pragma unroll
    for (int j = 0; j < 100; ++j) {
        float t = 0.0f;
#pragma unroll
        for (int i = 0; i < 10; ++i) t += b[i] * tw0[j * 10 + i];
        h[j] = silu_f(t);
    }
    const float* sp = s1 + src * 32;
    const float* vp = v1 + src * 96;   // (3,32)
    unsigned* mp = msg + (size_t)s * 64;
    for (int c = 0; c < 32; c += 2) {
        float w1a=0, w2a=0, w3a=0, w4a=0, w5a=0;
        float x1a=0, x2a=0, x3a=0, x4a=0, x5a=0;
        const float* r1 = tW + c * 100;
        const float* q1 = tW + (c+1) * 100;
        const float* r2 = tW + (32 + c) * 100;
        const float* q2 = tW + (33 + c) * 100;
        const float* r3 = tW + (64 + c) * 100;
        const float* q3 = tW + (65 + c) * 100;
        const float* r4 = tW + (96 + c) * 100;
        const float* q4 = tW + (97 + c) * 100;
        const float* r5 = tW + (128 + c) * 100;
        const float* q5 = tW + (129 + c) * 100;
#pragma unroll
        for (int j = 0; j < 100; ++j) {
            float hj = h[j];
            w1a += hj * r1[j]; x1a += hj * q1[j];
            w2a += hj * r2[j]; x2a += hj * q2[j];
            w3a += hj * r3[j]; x3a += hj * q3[j];
            w4a += hj * r4[j]; x4a += hj * q4[j];
            w5a += hj * r5[j]; x5a += hj * q5[j];
        }
        float s0 = sp[c], s1c = sp[c+1];
        float vx0 = vp[c],    vy0 = vp[32+c], vz0 = vp[64+c];
        float vx1 = vp[c+1],  vy1 = vp[33+c], vz1 = vp[65+c];
        float dot0 = vx0*c1 + vy0*c2 + vz0*c3;
        float dot1 = vx1*c1 + vy1*c2 + vz1*c3;
        float ms0 = w1a * s0 * cs0 + w2a * dot0;
        float ms1 = x1a * s1c * cs0 + x2a * dot1;
        float cx0 = vy0*c3 - vz0*c2, cy0 = vz0*c1 - vx0*c3, cz0 = vx0*c2 - vy0*c1;
        float cx1 = vy1*c3 - vz1*c2, cy1 = vz1*c1 - vx1*c3, cz1 = vx1*c2 - vy1*c1;
        float mx0 = w3a*s0*c1 + w4a*vx0*cs0 + w5a*cx0;
        float my0 = w3a*s0*c2 + w4a*vy0*cs0 + w5a*cy0;
        float mz0 = w3a*s0*c3 + w4a*vz0*cs0 + w5a*cz0;
        float mx1 = x3a*s1c*c1 + x4a*vx1*cs0 + x5a*cx1;
        float my1 = x3a*s1c*c2 + x4a*vy1*cs0 + x5a*cy1;
        float mz1 = x3a*s1c*c3 + x4a*vz1*cs0 + x5a*cz1;
        mp[c/2]      = pk(ms0, ms1);
        mp[16 + c/2] = pk(mx0, mx1);
        mp[32 + c/2] = pk(my0, my1);
        mp[48 + c/2] = pk(mz0, mz1);
    }
}

__global__ __launch_bounds__(256) void k_edge3s(
    const float4* __restrict__ geo,
    const float* __restrict__ tw0, const float* __restrict__ w1,
    const float* __restrict__ s2, const float* __restrict__ v2,
    unsigned* __restrict__ msg)
{
    int s = blockIdx.x * 256 + threadIdx.x;
    if (s >= EE) return;
    float4 g0 = geo[(size_t)s*4+0], g1 = geo[(size_t)s*4+1], g2 = geo[(size_t)s*4+2], g3 = geo[(size_t)s*4+3];
    float cs0 = g0.x, c1 = g0.y, c2 = g0.z, c3 = g0.w;
    float b[10] = {g1.x,g1.y,g1.z,g1.w,g2.x,g2.y,g2.z,g2.w,g3.x,g3.y};
    int src = __float_as_int(g3.z);

    float wk[64];
#pragma unroll
    for (int k = 0; k < 64; ++k) wk[k] = 0.0f;
    for (int j = 0; j < 100; ++j) {
        float t = 0.0f;
#pragma unroll
        for (int i = 0; i < 10; ++i) t += b[i] * tw0[j * 10 + i];
        float hj = silu_f(t);
#pragma unroll
        for (int k = 0; k < 64; ++k) wk[k] += hj * w1[j * 64 + k];
    }
    const float* sp = s2 + src * 32;
    const float* vp = v2 + src * 96;
    unsigned* mp = msg + (size_t)s * 16;
#pragma unroll
    for (int c = 0; c < 32; c += 2) {
        float d0 = vp[c]*c1 + vp[32+c]*c2 + vp[64+c]*c3;
        float d1 = vp[c+1]*c1 + vp[33+c]*c2 + vp[65+c]*c3;
        float m0 = wk[c]   * sp[c]   * cs0 + wk[32+c] * d0;
        float m1 = wk[c+1] * sp[c+1] * cs0 + wk[33+c] * d1;
        mp[c/2] = pk(m0, m1);
    }
}

// ---- segment sum of packed bf16 msgs -> fp32 node accumulators ----
template<int KU>
__global__ __launch_bounds__(256) void k_gather(
    const unsigned* __restrict__ msg, const int* __restrict__ rowp,
    float* __restrict__ a)
{
    int idx = blockIdx.x * 256 + threadIdx.x;
    int n = idx / KU;
    int k = idx - n * KU;
    if (n >= NN) return;
    int b0 = rowp[n], b1 = rowp[n + 1];
    float lo = 0.0f, hi = 0.0f;
    const unsigned* p = msg + (size_t)b0 * KU + k;
    for (int i = b0; i < b1; ++i) {
        unsigned u = *p; p += KU;
        lo += __uint_as_float(u << 16);
        hi += __uint_as_float(u & 0xffff0000u);
    }
    float2* ap = reinterpret_cast<float2*>(a) + (size_t)n * KU + k;
    *ap = make_float2(lo, hi);
}

// ================= node kernels =================
// a1 layout per node (64 floats): [ms 16][mvx 16][mvy 16][mvz 16]
__global__ __launch_bounds__(256) void k_node1(
    const float* __restrict__ x, const float* __restrict__ z,
    const float* __restrict__ a1,
    const float* __restrict__ sc1, const float* __restrict__ lin1s,
    const float* __restrict__ lin1v,
    float* __restrict__ s1, float* __restrict__ v1)
{
    int n = blockIdx.x * 256 + threadIdx.x;
    if (n >= NN) return;
    float zz = z[n];
    float xs[16], as[16];
#pragma unroll
    for (int c = 0; c < 16; ++c) {
        xs[c] = x[n * 16 + c] * zz;
        as[c] = a1[n * 64 + c] * INV_SQRT_NEIGH;
    }
    float sh[64];
#pragma unroll
    for (int o = 0; o < 64; ++o) sh[o] = 0.0f;
    for (int c = 0; c < 16; ++c) {
        float xc = xs[c], ac = as[c];
#pragma unroll
        for (int o = 0; o < 64; ++o)
            sh[o] += xc * sc1[c * 64 + o] + ac * lin1s[c * 64 + o];
    }
    float gate[32];
#pragma unroll
    for (int o = 0; o < 32; ++o) {
        s1[n * 32 + o] = silu_f(sh[o]);
        gate[o] = sigm_f(sh[32 + o]);
    }
    for (int i = 0; i < 3; ++i) {
        float av[16];
#pragma unroll
        for (int c = 0; c < 16; ++c) av[c] = a1[n * 64 + 16 + i * 16 + c] * INV_SQRT_NEIGH;
        float vh[32];
#pragma unroll
        for (int o = 0; o < 32; ++o) vh[o] = 0.0f;
        for (int c = 0; c < 16; ++c) {
            float ac = av[c];
#pragma unroll
            for (int o = 0; o < 32; ++o) vh[o] += ac * lin1v[c * 32 + o];
        }
#pragma unroll
        for (int o = 0; o < 32; ++o) v1[(n * 3 + i) * 32 + o] = vh[o] * gate[o];
    }
}

// a2 layout per node (128 floats): [ms 32][mvx 32][mvy 32][mvz 32]
__global__ __launch_bounds__(256) void k_node2(
    const float* __restrict__ z,
    const float* __restrict__ s1, const float* __restrict__ v1,
    const float* __restrict__ a2,
    const float* __restrict__ sc2s, const float* __restrict__ sc2v,
    const float* __restrict__ lin2s, const float* __restrict__ lin2v,
    float* __restrict__ s2, float* __restrict__ v2)
{
    int n = blockIdx.x * 256 + threadIdx.x;
    if (n >= NN) return;
    float zz = z[n];
    float sv[32], as[32];
#pragma unroll
    for (int c = 0; c < 32; ++c) {
        sv[c] = s1[n * 32 + c] * zz;
        as[c] = a2[n * 128 + c] * INV_SQRT_NEIGH;
    }
    float sh[64];
#pragma unroll
    for (int o = 0; o < 64; ++o) sh[o] = 0.0f;
    for (int c = 0; c < 32; ++c) {
        float a = sv[c], d = as[c];
#pragma unroll
        for (int o = 0; o < 64; ++o)
            sh[o] += a * sc2s[c * 64 + o] + d * lin2s[c * 64 + o];
    }
    float gate[32];
#pragma unroll
    for (int o = 0; o < 32; ++o) {
        s2[n * 32 + o] = silu_f(sh[o]);
        gate[o] = sigm_f(sh[32 + o]);
    }
    for (int i = 0; i < 3; ++i) {
        float vv[32], av[32];
#pragma unroll
        for (int c = 0; c < 32; ++c) {
            vv[c] = v1[(n * 3 + i) * 32 + c];
            av[c] = a2[n * 128 + 32 + i * 32 + c] * INV_SQRT_NEIGH;
        }
        float vh[32];
#pragma unroll
        for (int o = 0; o < 32; ++o) vh[o] = 0.0f;
        for (int c = 0; c < 32; ++c) {
            float a = vv[c], d = av[c];
#pragma unroll
            for (int o = 0; o < 32; ++o)
                vh[o] += a * sc2v[c * 32 + o] + d * lin2v[c * 32 + o];
        }
#pragma unroll
        for (int o = 0; o < 32; ++o) v2[(n * 3 + i) * 32 + o] = vh[o] * gate[o];
    }
}

// ---- output: one block per graph, LDS reduction, plain writes ----
__global__ __launch_bounds__(256) void k_out(
    const float* __restrict__ z, const int* __restrict__ gstart,
    const float* __restrict__ s2, const float* __restrict__ a3,
    const float* __restrict__ sco, const float* __restrict__ lino,
    float* __restrict__ out)
{
    __shared__ float red[100];
    int g = blockIdx.x;
    int t = threadIdx.x;
    if (t < 100) red[t] = 0.0f;
    __syncthreads();
    int n0 = gstart[g], n1 = gstart[g + 1];
    float acc[100];
#pragma unroll
    for (int o = 0; o < 100; ++o) acc[o] = 0.0f;
    for (int n = n0 + t; n < n1; n += 256) {
        float zz = z[n];
        for (int c = 0; c < 32; ++c) {
            float a = s2[n * 32 + c] * zz;
            float d = a3[n * 32 + c] * INV_SQRT_NEIGH;
#pragma unroll
            for (int o = 0; o < 100; ++o)
                acc[o] += a * sco[c * 100 + o] + d * lino[c * 100 + o];
        }
    }
#pragma unroll
    for (int o = 0; o < 100; ++o) atomicAdd(&red[o], acc[o]);
    __syncthreads();
    if (t < 100) out[g * 100 + t] = red[t] * INV_SQRT_NODES;
}

// ================= fallback (atomic scatter) edge kernels =================
__global__ __launch_bounds__(256) void ka_edge1(
    const float* __restrict__ pos, const float* __restrict__ x,
    const int* __restrict__ ei, const float* __restrict__ eshift,
    const float* __restrict__ lat, const int* __restrict__ batch,
    const float* __restrict__ tw0, const float* __restrict__ w1,
    float* __restrict__ a1)
{
    int e = blockIdx.x * 256 + threadIdx.x;
    if (e >= EE) return;
    int src, dst; float cs0, csh[3], b[10];
    edge_features(e, pos, ei, eshift, lat, batch, src, dst, cs0, csh, b);
    float wk[32];
#pragma unroll
    for (int k = 0; k < 32; ++k) wk[k] = 0.0f;
    for (int j = 0; j < 100; ++j) {
        float t = 0.0f;
#pragma unroll
        for (int i = 0; i < 10; ++i) t += b[i] * tw0[j * 10 + i];
        float hj = silu_f(t);
#pragma unroll
        for (int k = 0; k < 32; ++k) wk[k] += hj * w1[j * 32 + k];
    }
    const float* xp = x + src * 16;
    float* ap = a1 + (size_t)dst * 64;
#pragma unroll
    for (int k = 0; k < 16; ++k) {
        float xs = xp[k];
        unsafeAtomicAdd(ap + k, wk[k] * xs * cs0);
        float mv = wk[16 + k] * xs;
        unsafeAtomicAdd(ap + 16 + k, mv * csh[0]);
        unsafeAtomicAdd(ap + 32 + k, mv * csh[1]);
        unsafeAtomicAdd(ap + 48 + k, mv * csh[2]);
    }
}

__global__ __launch_bounds__(256) void ka_edge2(
    const float* __restrict__ pos, const int* __restrict__ ei,
    const float* __restrict__ eshift, const float* __restrict__ lat,
    const int* __restrict__ batch,
    const float* __restrict__ tw0, const float* __restrict__ tW,
    const float* __restrict__ s1, const float* __restrict__ v1,
    float* __restrict__ a2)
{
    int e = blockIdx.x * 256 + threadIdx.x;
    if (e >= EE) return;
    int src, dst; float cs0, csh[3], b[10];
    edge_features(e, pos, ei, eshift, lat, batch, src, dst, cs0, csh, b);
    float h[100];
#pragma unroll
    for (int j = 0; j < 100; ++j) {
        float t = 0.0f;
#pragma unroll
        for (int i = 0; i < 10; ++i) t += b[i] * tw0[j * 10 + i];
        h[j] = silu_f(t);
    }
    const float* sp = s1 + src * 32;
    const float* vp = v1 + src * 96;
    float* ap = a2 + (size_t)dst * 128;
    for (int c = 0; c < 32; ++c) {
        float w1a = 0, w2a = 0, w3a = 0, w4a = 0, w5a = 0;
        const float* r1 = tW + c * 100;
        const float* r2 = tW + (32 + c) * 100;
        const float* r3 = tW + (64 + c) * 100;
        const float* r4 = tW + (96 + c) * 100;
        const float* r5 = tW + (128 + c) * 100;
#pragma unroll
        for (int j = 0; j < 100; ++j) {
            float hj = h[j];
            w1a += hj * r1[j]; w2a += hj * r2[j]; w3a += hj * r3[j];
            w4a += hj * r4[j]; w5a += hj * r5[j];
        }
        float ssc = sp[c];
        float vx = vp[c], vy = vp[32 + c], vz = vp[64 + c];
        float dotv = vx * csh[0] + vy * csh[1] + vz * csh[2];
        unsafeAtomicAdd(ap + c, w1a * ssc * cs0 + w2a * dotv);
        float cx = vy * csh[2] - vz * csh[1];
        float cy = vz * csh[0] - vx * csh[2];
        float cz = vx * csh[1] - vy * csh[0];
        unsafeAtomicAdd(ap + 32 + c, w3a * ssc * csh[0] + w4a * vx * cs0 + w5a * cx);
        unsafeAtomicAdd(ap + 64 + c, w3a * ssc * csh[1] + w4a * vy * cs0 + w5a * cy);
        unsafeAtomicAdd(ap + 96 + c, w3a * ssc * csh[2] + w4a * vz * cs0 + w5a * cz);
    }
}

__global__ __launch_bounds__(256) void ka_edge3(
    const float* __restrict__ pos, const int* __restrict__ ei,
    const float* __restrict__ eshift, const float* __restrict__ lat,
    const int* __restrict__ batch,
    const float* __restrict__ tw0, const float* __restrict__ w1,
    const float* __restrict__ s2, const float* __restrict__ v2,
    float* __restrict__ a3)
{
    int e = blockIdx.x * 256 + threadIdx.x;
    if (e >= EE) return;
    int src, dst; float cs0, csh[3], b[10];
    edge_features(e, pos, ei, eshift, lat, batch, src, dst, cs0, csh, b);
    float wk[64];
#pragma unroll
    for (int k = 0; k < 64; ++k) wk[k] = 0.0f;
    for (int j = 0; j < 100; ++j) {
        float t = 0.0f;
#pragma unroll
        for (int i = 0; i < 10; ++i) t += b[i] * tw0[j * 10 + i];
        float hj = silu_f(t);
#pragma unroll
        for (int k = 0; k < 64; ++k) wk[k] += hj * w1[j * 64 + k];
    }
    const float* sp = s2 + src * 32;
    const float* vp = v2 + src * 96;
    float* ap = a3 + (size_t)dst * 32;
#pragma unroll
    for (int c = 0; c < 32; ++c) {
        float dotv = vp[c] * csh[0] + vp[32 + c] * csh[1] + vp[64 + c] * csh[2];
        unsafeAtomicAdd(ap + c, wk[c] * sp[c] * cs0 + wk[32 + c] * dotv);
    }
}

// ================= launcher =================
extern "C" void kernel_launch(void* const* d_in, const int* in_sizes, int n_in,
                              void* d_out, int out_size, void* d_ws, size_t ws_size,
                              hipStream_t stream)
{
    const float* pos   = (const float*)d_in[0];
    const float* x     = (const float*)d_in[1];
    const float* z     = (const float*)d_in[2];
    const int*   ei    = (const int*)d_in[3];
    const float* esh   = (const float*)d_in[4];
    const float* lat   = (const float*)d_in[5];
    const int*   batch = (const int*)d_in[6];
    const float* fc1w0 = (const float*)d_in[7];
    const float* fc1w1 = (const float*)d_in[8];
    const float* sc1   = (const float*)d_in[9];
    const float* lin1s = (const float*)d_in[10];
    const float* lin1v = (const float*)d_in[11];
    const float* fc2w0 = (const float*)d_in[12];
    const float* fc2w1 = (const float*)d_in[13];
    const float* sc2s  = (const float*)d_in[14];
    const float* sc2v  = (const float*)d_in[15];
    const float* lin2s = (const float*)d_in[16];
    const float* lin2v = (const float*)d_in[17];
    const float* fcow0 = (const float*)d_in[18];
    const float* fcow1 = (const float*)d_in[19];
    const float* sco   = (const float*)d_in[20];
    const float* lino  = (const float*)d_in[21];
    float* out = (float*)d_out;

    char* cur = (char*)d_ws;
    auto alloc = [&](size_t bytes) { char* r = cur; cur += (bytes + 15) & ~(size_t)15; return r; };

    float* a1  = (float*)alloc((size_t)NN * 64 * 4);
    float* a2  = (float*)alloc((size_t)NN * 128 * 4);
    float* a3  = (float*)alloc((size_t)NN * 32 * 4);
    float* s1  = (float*)alloc((size_t)NN * 32 * 4);
    float* v1  = (float*)alloc((size_t)NN * 96 * 4);
    float* s2  = (float*)alloc((size_t)NN * 32 * 4);
    float* v2  = (float*)alloc((size_t)NN * 96 * 4);
    float* t10 = (float*)alloc(1000 * 4);
    float* t20 = (float*)alloc(1000 * 4);
    float* to0 = (float*)alloc(1000 * 4);
    float* t21 = (float*)alloc(16000 * 4);
    int* deg    = (int*)alloc((size_t)NN * 4);
    int* rowp   = (int*)alloc((size_t)(NN + 4) * 4);
    int* cursor = (int*)alloc((size_t)NN * 4);
    int* bsum   = (int*)alloc(256 * 4);
    int* boff   = (int*)alloc(256 * 4);
    int* gstart = (int*)alloc(68 * 4);
    size_t base_need = (size_t)(cur - (char*)d_ws);
    float4*   geo = (float4*)alloc((size_t)EE * 16 * 4);
    unsigned* msg = (unsigned*)alloc((size_t)EE * 64 * 4);
    size_t csr_need = (size_t)(cur - (char*)d_ws);

    k_prep<<<75, 256, 0, stream>>>(fc1w0, fc2w0, fcow0, fc2w1, t10, t20, to0, t21);
    k_gb<<<NB_N, 256, 0, stream>>>(batch, gstart);

    if (ws_size >= csr_need) {
        // ---- CSR path: no scatter atomics ----
        hipMemsetAsync(deg, 0, (size_t)NN * 4, stream);
        k_hist <<<NB_E, 256, 0, stream>>>(ei, deg);
        k_scan1<<<NB_N, 256, 0, stream>>>(deg, bsum);
        k_scan2<<<1, 64, 0, stream>>>(bsum, boff, rowp);
        k_scan3<<<NB_N, 256, 0, stream>>>(deg, boff, rowp, cursor);
        k_geom <<<NB_E, 256, 0, stream>>>(pos, ei, esh, lat, batch, cursor, geo);

        k_edge1s<<<NB_E, 256, 0, stream>>>(geo, x, t10, fc1w1, msg);
        k_gather<32><<<(NN * 32 + 255) / 256, 256, 0, stream>>>(msg, rowp, a1);
        k_node1<<<NB_N, 256, 0, stream>>>(x, z, a1, sc1, lin1s, lin1v, s1, v1);

        k_edge2s<<<NB_E, 256, 0, stream>>>(geo, t20, t21, s1, v1, msg);
        k_gather<64><<<(NN * 64 + 255) / 256, 256, 0, stream>>>(msg, rowp, a2);
        k_node2<<<NB_N, 256, 0, stream>>>(z, s1, v1, a2, sc2s, sc2v, lin2s, lin2v, s2, v2);

        k_edge3s<<<NB_E, 256, 0, stream>>>(geo, to0, fcow1, s2, v2, msg);
        k_gather<16><<<(NN * 16 + 255) / 256, 256, 0, stream>>>(msg, rowp, a3);
        k_out<<<NGRAPHS, 256, 0, stream>>>(z, gstart, s2, a3, sco, lino, out);
    } else {
        // ---- fallback: atomic scatter (round-0 structure) ----
        (void)base_need;
        hipMemsetAsync(a1, 0, (size_t)NN * 224 * 4, stream);  // a1,a2,a3 contiguous
        ka_edge1<<<NB_E, 256, 0, stream>>>(pos, x, ei, esh, lat, batch, t10, fc1w1, a1);
        k_node1<<<NB_N, 256, 0, stream>>>(x, z, a1, sc1, lin1s, lin1v, s1, v1);
        ka_edge2<<<NB_E, 256, 0, stream>>>(pos, ei, esh, lat, batch, t20, t21, s1, v1, a2);
        k_node2<<<NB_N, 256, 0, stream>>>(z, s1, v1, a2, sc2s, sc2v, lin2s, lin2v, s2, v2);
        ka_edge3<<<NB_E, 256, 0, stream>>>(pos, ei, esh, lat, batch, to0, fcow1, s2, v2, a3);
        k_out<<<NGRAPHS, 256, 0, stream>>>(z, gstart, s2, a3, sco, lino, out);
    }
}

// Round 3
// 3685.285 us; speedup vs baseline: 3.3935x; 3.2570x over previous
//
#include <hip/hip_runtime.h>
#include <hip/hip_bf16.h>

#define NN 50000
#define EE 1000000
#define NGRAPHS 64
#define OUTD 100
#define NB_N 196        // (NN+255)/256
#define NB_E 3907       // (EE+255)/256

#define INV_SQRT_NEIGH 0.22360679774997896f   // 1/sqrt(20)
#define INV_SQRT_NODES 0.035777087639996634f  // 1/sqrt(781.25)
#define SQRT3 1.7320508075688772f
#define BSCALE 2.8234621879136734f            // sqrt(10)/1.12
#define BSTEP 0.3888888888888889f             // 3.5/9
#define INV_BSTEP 2.5714285714285716f
#define PI_F 3.14159265358979323846f

__device__ __forceinline__ float silu_f(float x) { return x / (1.0f + __expf(-x)); }
__device__ __forceinline__ float sigm_f(float x) { return 1.0f / (1.0f + __expf(-x)); }

// pack two fp32 -> bf16 pair (RTNE) in one uint
__device__ __forceinline__ unsigned pk(float a, float b) {
    union { float f; unsigned u; } ua, ub; ua.f = a; ub.f = b;
    unsigned x = ua.u + 0x7fffu + ((ua.u >> 16) & 1u);
    unsigned y = ub.u + 0x7fffu + ((ub.u >> 16) & 1u);
    return (x >> 16) | (y & 0xffff0000u);
}

// ---- per-edge geometry: cutoff*Y0, cutoff*Y1, gaussian basis ----
__device__ __forceinline__ void edge_features(
    int e, const float* __restrict__ pos, const int* __restrict__ ei,
    const float* __restrict__ eshift, const float* __restrict__ lat,
    const int* __restrict__ batch,
    int& src, int& dst, float& cs0, float* csh1, float* b)
{
    src = ei[e];
    dst = ei[EE + e];
    int g = batch[src];
    const float* L = lat + g * 9;
    float t0 = eshift[e*3+0], t1 = eshift[e*3+1], t2 = eshift[e*3+2];
    float vx = pos[dst*3+0] - pos[src*3+0] + t0*L[0] + t1*L[3] + t2*L[6];
    float vy = pos[dst*3+1] - pos[src*3+1] + t0*L[1] + t1*L[4] + t2*L[7];
    float vz = pos[dst*3+2] - pos[src*3+2] + t0*L[2] + t1*L[5] + t2*L[8];
    float r = sqrtf(vx*vx + vy*vy + vz*vz);
    float u = 2.0f * (r * (1.0f/3.5f) - 1.0f);
    float cut;
    if (u > 0.0f) cut = 0.0f;
    else if (u < -2.0f) cut = 1.0f;
    else cut = 0.5f * (1.0f - __cosf(PI_F * u));
    cs0 = cut;
    float inv = 1.0f / fmaxf(r, 1e-12f);
    float sc = SQRT3 * cut * inv;
    csh1[0] = sc * vx; csh1[1] = sc * vy; csh1[2] = sc * vz;
#pragma unroll
    for (int i = 0; i < 10; ++i) {
        float d = (r - (float)i * BSTEP) * INV_BSTEP;
        b[i] = __expf(-d * d) * BSCALE;
    }
}

// ---- prep: transpose small weights for contiguous row reads ----
__global__ __launch_bounds__(256) void k_prep(
    const float* __restrict__ fc1w0, const float* __restrict__ fc2w0,
    const float* __restrict__ fcow0, const float* __restrict__ fc2w1,
    float* __restrict__ t10, float* __restrict__ t20,
    float* __restrict__ to0, float* __restrict__ t21)
{
    int idx = blockIdx.x * 256 + threadIdx.x;
    if (idx < 1000) {                    // (10,100) -> (100,10)
        int j = idx / 10, i = idx % 10;
        t10[idx] = fc1w0[i * 100 + j];
    } else if (idx < 2000) {
        int t = idx - 1000; int j = t / 10, i = t % 10;
        t20[t] = fc2w0[i * 100 + j];
    } else if (idx < 3000) {
        int t = idx - 2000; int j = t / 10, i = t % 10;
        to0[t] = fcow0[i * 100 + j];
    } else if (idx < 19000) {            // (100,160) -> (160,100)
        int t = idx - 3000; int k = t / 100, j = t % 100;
        t21[t] = fc2w1[j * 160 + k];
    }
}

// ================= CSR build =================
__global__ __launch_bounds__(256) void k_hist(const int* __restrict__ ei, int* __restrict__ deg)
{
    int e = blockIdx.x * 256 + threadIdx.x;
    if (e < EE) atomicAdd(&deg[ei[EE + e]], 1);
}

__global__ __launch_bounds__(256) void k_scan1(const int* __restrict__ deg, int* __restrict__ bsum)
{
    __shared__ int sd[256];
    int t = threadIdx.x;
    int i = blockIdx.x * 256 + t;
    sd[t] = (i < NN) ? deg[i] : 0;
    __syncthreads();
#pragma unroll
    for (int o = 128; o > 0; o >>= 1) {
        if (t < o) sd[t] += sd[t + o];
        __syncthreads();
    }
    if (t == 0) bsum[blockIdx.x] = sd[0];
}

__global__ void k_scan2(const int* __restrict__ bsum, int* __restrict__ boff, int* __restrict__ rowp)
{
    if (threadIdx.x == 0) {
        int acc = 0;
        for (int b = 0; b < NB_N; ++b) { boff[b] = acc; acc += bsum[b]; }
        rowp[NN] = EE;
    }
}

__global__ __launch_bounds__(256) void k_scan3(
    const int* __restrict__ deg, const int* __restrict__ boff,
    int* __restrict__ rowp, int* __restrict__ cursor)
{
    __shared__ int sd[256];
    int t = threadIdx.x;
    int i = blockIdx.x * 256 + t;
    int v = (i < NN) ? deg[i] : 0;
    sd[t] = v;
    __syncthreads();
#pragma unroll
    for (int o = 1; o < 256; o <<= 1) {
        int xv = 0;
        if (t >= o) xv = sd[t - o];
        __syncthreads();
        sd[t] += xv;
        __syncthreads();
    }
    if (i < NN) {
        int val = boff[blockIdx.x] + sd[t] - v;   // exclusive
        rowp[i] = val;
        cursor[i] = val;
    }
}

// slot -> original edge id (dst-sorted)
__global__ __launch_bounds__(256) void k_fill(
    const int* __restrict__ ei, int* __restrict__ cursor, int* __restrict__ eperm)
{
    int e = blockIdx.x * 256 + threadIdx.x;
    if (e >= EE) return;
    int slot = atomicAdd(&cursor[ei[EE + e]], 1);
    eperm[slot] = e;
}

// graph boundaries from sorted batch
__global__ __launch_bounds__(256) void k_gb(const int* __restrict__ batch, int* __restrict__ gstart)
{
    int n = blockIdx.x * 256 + threadIdx.x;
    if (n >= NN) return;
    int b = batch[n];
    if (n == 0) { for (int g = 0; g <= b; ++g) gstart[g] = 0; }
    else {
        int pb = batch[n - 1];
        for (int g = pb + 1; g <= b; ++g) gstart[g] = n;
    }
    if (n == NN - 1) { for (int g = b + 1; g <= NGRAPHS; ++g) gstart[g] = NN; }
}

// ================= chunked edge kernels (slot order, bf16 msgs, no atomics) =================
__global__ __launch_bounds__(256) void k_edge1c(
    int c0, int m,
    const float* __restrict__ pos, const float* __restrict__ x,
    const int* __restrict__ ei, const float* __restrict__ esh,
    const float* __restrict__ lat, const int* __restrict__ batch,
    const int* __restrict__ eperm,
    const float* __restrict__ tw0, const float* __restrict__ w1,
    unsigned* __restrict__ msg)
{
    int t = blockIdx.x * 256 + threadIdx.x;
    if (t >= m) return;
    int e = eperm[c0 + t];
    int src, dst; float cs0, csh[3], b[10];
    edge_features(e, pos, ei, esh, lat, batch, src, dst, cs0, csh, b);

    float wk[32];
#pragma unroll
    for (int k = 0; k < 32; ++k) wk[k] = 0.0f;
    for (int j = 0; j < 100; ++j) {
        float a = 0.0f;
#pragma unroll
        for (int i = 0; i < 10; ++i) a += b[i] * tw0[j * 10 + i];
        float hj = silu_f(a);
#pragma unroll
        for (int k = 0; k < 32; ++k) wk[k] += hj * w1[j * 32 + k];
    }
    const float* xp = x + src * 16;
    unsigned* mp = msg + (size_t)t * 32;
#pragma unroll
    for (int c = 0; c < 16; c += 2) {
        float x0 = xp[c], x1 = xp[c+1];
        float ms0 = wk[c] * x0 * cs0,   ms1 = wk[c+1] * x1 * cs0;
        float m0  = wk[16+c] * x0,      m1  = wk[17+c] * x1;
        mp[c/2]      = pk(ms0, ms1);
        mp[8 + c/2]  = pk(m0*csh[0], m1*csh[0]);
        mp[16 + c/2] = pk(m0*csh[1], m1*csh[1]);
        mp[24 + c/2] = pk(m0*csh[2], m1*csh[2]);
    }
}

__global__ __launch_bounds__(256, 2) void k_edge2c(
    int c0, int m,
    const float* __restrict__ pos, const int* __restrict__ ei,
    const float* __restrict__ esh, const float* __restrict__ lat,
    const int* __restrict__ batch, const int* __restrict__ eperm,
    const float* __restrict__ tw0, const float* __restrict__ tW,
    const float* __restrict__ s1, const float* __restrict__ v1,
    unsigned* __restrict__ msg)
{
    int t = blockIdx.x * 256 + threadIdx.x;
    if (t >= m) return;
    int e = eperm[c0 + t];
    int src, dst; float cs0, csh[3], b[10];
    edge_features(e, pos, ei, esh, lat, batch, src, dst, cs0, csh, b);
    float c1 = csh[0], c2 = csh[1], c3 = csh[2];

    float h[100];
#pragma unroll
    for (int j = 0; j < 100; ++j) {
        float a = 0.0f;
#pragma unroll
        for (int i = 0; i < 10; ++i) a += b[i] * tw0[j * 10 + i];
        h[j] = silu_f(a);
    }
    const float* sp = s1 + src * 32;
    const float* vp = v1 + src * 96;   // (3,32)
    unsigned* mp = msg + (size_t)t * 64;
    for (int c = 0; c < 32; c += 2) {
        float w1a=0, w2a=0, w3a=0, w4a=0, w5a=0;
        float x1a=0, x2a=0, x3a=0, x4a=0, x5a=0;
        const float* r1 = tW + c * 100;
        const float* q1 = tW + (c+1) * 100;
        const float* r2 = tW + (32 + c) * 100;
        const float* q2 = tW + (33 + c) * 100;
        const float* r3 = tW + (64 + c) * 100;
        const float* q3 = tW + (65 + c) * 100;
        const float* r4 = tW + (96 + c) * 100;
        const float* q4 = tW + (97 + c) * 100;
        const float* r5 = tW + (128 + c) * 100;
        const float* q5 = tW + (129 + c) * 100;
#pragma unroll
        for (int j = 0; j < 100; ++j) {
            float hj = h[j];
            w1a += hj * r1[j]; x1a += hj * q1[j];
            w2a += hj * r2[j]; x2a += hj * q2[j];
            w3a += hj * r3[j]; x3a += hj * q3[j];
            w4a += hj * r4[j]; x4a += hj * q4[j];
            w5a += hj * r5[j]; x5a += hj * q5[j];
        }
        float s0 = sp[c], s1c = sp[c+1];
        float vx0 = vp[c],    vy0 = vp[32+c], vz0 = vp[64+c];
        float vx1 = vp[c+1],  vy1 = vp[33+c], vz1 = vp[65+c];
        float dot0 = vx0*c1 + vy0*c2 + vz0*c3;
        float dot1 = vx1*c1 + vy1*c2 + vz1*c3;
        float ms0 = w1a * s0 * cs0 + w2a * dot0;
        float ms1 = x1a * s1c * cs0 + x2a * dot1;
        float cx0 = vy0*c3 - vz0*c2, cy0 = vz0*c1 - vx0*c3, cz0 = vx0*c2 - vy0*c1;
        float cx1 = vy1*c3 - vz1*c2, cy1 = vz1*c1 - vx1*c3, cz1 = vx1*c2 - vy1*c1;
        float mx0 = w3a*s0*c1 + w4a*vx0*cs0 + w5a*cx0;
        float my0 = w3a*s0*c2 + w4a*vy0*cs0 + w5a*cy0;
        float mz0 = w3a*s0*c3 + w4a*vz0*cs0 + w5a*cz0;
        float mx1 = x3a*s1c*c1 + x4a*vx1*cs0 + x5a*cx1;
        float my1 = x3a*s1c*c2 + x4a*vy1*cs0 + x5a*cy1;
        float mz1 = x3a*s1c*c3 + x4a*vz1*cs0 + x5a*cz1;
        mp[c/2]      = pk(ms0, ms1);
        mp[16 + c/2] = pk(mx0, mx1);
        mp[32 + c/2] = pk(my0, my1);
        mp[48 + c/2] = pk(mz0, mz1);
    }
}

__global__ __launch_bounds__(256) void k_edge3c(
    int c0, int m,
    const float* __restrict__ pos, const int* __restrict__ ei,
    const float* __restrict__ esh, const float* __restrict__ lat,
    const int* __restrict__ batch, const int* __restrict__ eperm,
    const float* __restrict__ tw0, const float* __restrict__ w1,
    const float* __restrict__ s2, const float* __restrict__ v2,
    unsigned* __restrict__ msg)
{
    int t = blockIdx.x * 256 + threadIdx.x;
    if (t >= m) return;
    int e = eperm[c0 + t];
    int src, dst; float cs0, csh[3], b[10];
    edge_features(e, pos, ei, esh, lat, batch, src, dst, cs0, csh, b);

    float wk[64];
#pragma unroll
    for (int k = 0; k < 64; ++k) wk[k] = 0.0f;
    for (int j = 0; j < 100; ++j) {
        float a = 0.0f;
#pragma unroll
        for (int i = 0; i < 10; ++i) a += b[i] * tw0[j * 10 + i];
        float hj = silu_f(a);
#pragma unroll
        for (int k = 0; k < 64; ++k) wk[k] += hj * w1[j * 64 + k];
    }
    const float* sp = s2 + src * 32;
    const float* vp = v2 + src * 96;
    unsigned* mp = msg + (size_t)t * 16;
#pragma unroll
    for (int c = 0; c < 32; c += 2) {
        float d0 = vp[c]*csh[0] + vp[32+c]*csh[1] + vp[64+c]*csh[2];
        float d1 = vp[c+1]*csh[0] + vp[33+c]*csh[1] + vp[65+c]*csh[2];
        float m0 = wk[c]   * sp[c]   * cs0 + wk[32+c] * d0;
        float m1 = wk[c+1] * sp[c+1] * cs0 + wk[33+c] * d1;
        mp[c/2] = pk(m0, m1);
    }
}

// ---- clamped segment sum of packed bf16 msgs, += into fp32 accumulators ----
template<int KU>
__global__ __launch_bounds__(256) void k_gatherc(
    const unsigned* __restrict__ msg, const int* __restrict__ rowp,
    float* __restrict__ a, int c0, int c1)
{
    int idx = blockIdx.x * 256 + threadIdx.x;
    int n = idx / KU;
    int k = idx - n * KU;
    if (n >= NN) return;
    int b0 = rowp[n], b1 = rowp[n + 1];
    int lo = b0 > c0 ? b0 : c0;
    int hi = b1 < c1 ? b1 : c1;
    if (lo >= hi) return;
    float losum = 0.0f, hisum = 0.0f;
    const unsigned* p = msg + (size_t)(lo - c0) * KU + k;
    for (int i = lo; i < hi; ++i) {
        unsigned u = *p; p += KU;
        losum += __uint_as_float(u << 16);
        hisum += __uint_as_float(u & 0xffff0000u);
    }
    float2* ap = reinterpret_cast<float2*>(a) + (size_t)n * KU + k;
    float2 cv = *ap;
    cv.x += losum; cv.y += hisum;
    *ap = cv;
}

// ================= node kernels =================
// a1 layout per node (64 floats): [ms 16][mvx 16][mvy 16][mvz 16]
__global__ __launch_bounds__(256) void k_node1(
    const float* __restrict__ x, const float* __restrict__ z,
    const float* __restrict__ a1,
    const float* __restrict__ sc1, const float* __restrict__ lin1s,
    const float* __restrict__ lin1v,
    float* __restrict__ s1, float* __restrict__ v1)
{
    int n = blockIdx.x * 256 + threadIdx.x;
    if (n >= NN) return;
    float zz = z[n];
    float xs[16], as[16];
#pragma unroll
    for (int c = 0; c < 16; ++c) {
        xs[c] = x[n * 16 + c] * zz;
        as[c] = a1[n * 64 + c] * INV_SQRT_NEIGH;
    }
    float sh[64];
#pragma unroll
    for (int o = 0; o < 64; ++o) sh[o] = 0.0f;
    for (int c = 0; c < 16; ++c) {
        float xc = xs[c], ac = as[c];
#pragma unroll
        for (int o = 0; o < 64; ++o)
            sh[o] += xc * sc1[c * 64 + o] + ac * lin1s[c * 64 + o];
    }
    float gate[32];
#pragma unroll
    for (int o = 0; o < 32; ++o) {
        s1[n * 32 + o] = silu_f(sh[o]);
        gate[o] = sigm_f(sh[32 + o]);
    }
    for (int i = 0; i < 3; ++i) {
        float av[16];
#pragma unroll
        for (int c = 0; c < 16; ++c) av[c] = a1[n * 64 + 16 + i * 16 + c] * INV_SQRT_NEIGH;
        float vh[32];
#pragma unroll
        for (int o = 0; o < 32; ++o) vh[o] = 0.0f;
        for (int c = 0; c < 16; ++c) {
            float ac = av[c];
#pragma unroll
            for (int o = 0; o < 32; ++o) vh[o] += ac * lin1v[c * 32 + o];
        }
#pragma unroll
        for (int o = 0; o < 32; ++o) v1[(n * 3 + i) * 32 + o] = vh[o] * gate[o];
    }
}

// a2 layout per node (128 floats): [ms 32][mvx 32][mvy 32][mvz 32]
__global__ __launch_bounds__(256) void k_node2(
    const float* __restrict__ z,
    const float* __restrict__ s1, const float* __restrict__ v1,
    const float* __restrict__ a2,
    const float* __restrict__ sc2s, const float* __restrict__ sc2v,
    const float* __restrict__ lin2s, const float* __restrict__ lin2v,
    float* __restrict__ s2, float* __restrict__ v2)
{
    int n = blockIdx.x * 256 + threadIdx.x;
    if (n >= NN) return;
    float zz = z[n];
    float sv[32], as[32];
#pragma unroll
    for (int c = 0; c < 32; ++c) {
        sv[c] = s1[n * 32 + c] * zz;
        as[c] = a2[n * 128 + c] * INV_SQRT_NEIGH;
    }
    float sh[64];
#pragma unroll
    for (int o = 0; o < 64; ++o) sh[o] = 0.0f;
    for (int c = 0; c < 32; ++c) {
        float a = sv[c], d = as[c];
#pragma unroll
        for (int o = 0; o < 64; ++o)
            sh[o] += a * sc2s[c * 64 + o] + d * lin2s[c * 64 + o];
    }
    float gate[32];
#pragma unroll
    for (int o = 0; o < 32; ++o) {
        s2[n * 32 + o] = silu_f(sh[o]);
        gate[o] = sigm_f(sh[32 + o]);
    }
    for (int i = 0; i < 3; ++i) {
        float vv[32], av[32];
#pragma unroll
        for (int c = 0; c < 32; ++c) {
            vv[c] = v1[(n * 3 + i) * 32 + c];
            av[c] = a2[n * 128 + 32 + i * 32 + c] * INV_SQRT_NEIGH;
        }
        float vh[32];
#pragma unroll
        for (int o = 0; o < 32; ++o) vh[o] = 0.0f;
        for (int c = 0; c < 32; ++c) {
            float a = vv[c], d = av[c];
#pragma unroll
            for (int o = 0; o < 32; ++o)
                vh[o] += a * sc2v[c * 32 + o] + d * lin2v[c * 32 + o];
        }
#pragma unroll
        for (int o = 0; o < 32; ++o) v2[(n * 3 + i) * 32 + o] = vh[o] * gate[o];
    }
}

// ---- output: one block per graph, LDS reduction, plain writes ----
__global__ __launch_bounds__(256) void k_out(
    const float* __restrict__ z, const int* __restrict__ gstart,
    const float* __restrict__ s2, const float* __restrict__ a3,
    const float* __restrict__ sco, const float* __restrict__ lino,
    float* __restrict__ out)
{
    __shared__ float red[100];
    int g = blockIdx.x;
    int t = threadIdx.x;
    if (t < 100) red[t] = 0.0f;
    __syncthreads();
    int n0 = gstart[g], n1 = gstart[g + 1];
    float acc[100];
#pragma unroll
    for (int o = 0; o < 100; ++o) acc[o] = 0.0f;
    for (int n = n0 + t; n < n1; n += 256) {
        float zz = z[n];
        for (int c = 0; c < 32; ++c) {
            float a = s2[n * 32 + c] * zz;
            float d = a3[n * 32 + c] * INV_SQRT_NEIGH;
#pragma unroll
            for (int o = 0; o < 100; ++o)
                acc[o] += a * sco[c * 100 + o] + d * lino[c * 100 + o];
        }
    }
#pragma unroll
    for (int o = 0; o < 100; ++o) atomicAdd(&red[o], acc[o]);
    __syncthreads();
    if (t < 100) out[g * 100 + t] = red[t] * INV_SQRT_NODES;
}

// ================= fallback (atomic scatter) edge kernels =================
__global__ __launch_bounds__(256) void ka_edge1(
    const float* __restrict__ pos, const float* __restrict__ x,
    const int* __restrict__ ei, const float* __restrict__ eshift,
    const float* __restrict__ lat, const int* __restrict__ batch,
    const float* __restrict__ tw0, const float* __restrict__ w1,
    float* __restrict__ a1)
{
    int e = blockIdx.x * 256 + threadIdx.x;
    if (e >= EE) return;
    int src, dst; float cs0, csh[3], b[10];
    edge_features(e, pos, ei, eshift, lat, batch, src, dst, cs0, csh, b);
    float wk[32];
#pragma unroll
    for (int k = 0; k < 32; ++k) wk[k] = 0.0f;
    for (int j = 0; j < 100; ++j) {
        float a = 0.0f;
#pragma unroll
        for (int i = 0; i < 10; ++i) a += b[i] * tw0[j * 10 + i];
        float hj = silu_f(a);
#pragma unroll
        for (int k = 0; k < 32; ++k) wk[k] += hj * w1[j * 32 + k];
    }
    const float* xp = x + src * 16;
    float* ap = a1 + (size_t)dst * 64;
#pragma unroll
    for (int k = 0; k < 16; ++k) {
        float xs = xp[k];
        unsafeAtomicAdd(ap + k, wk[k] * xs * cs0);
        float mv = wk[16 + k] * xs;
        unsafeAtomicAdd(ap + 16 + k, mv * csh[0]);
        unsafeAtomicAdd(ap + 32 + k, mv * csh[1]);
        unsafeAtomicAdd(ap + 48 + k, mv * csh[2]);
    }
}

__global__ __launch_bounds__(256) void ka_edge2(
    const float* __restrict__ pos, const int* __restrict__ ei,
    const float* __restrict__ eshift, const float* __restrict__ lat,
    const int* __restrict__ batch,
    const float* __restrict__ tw0, const float* __restrict__ tW,
    const float* __restrict__ s1, const float* __restrict__ v1,
    float* __restrict__ a2)
{
    int e = blockIdx.x * 256 + threadIdx.x;
    if (e >= EE) return;
    int src, dst; float cs0, csh[3], b[10];
    edge_features(e, pos, ei, eshift, lat, batch, src, dst, cs0, csh, b);
    float h[100];
#pragma unroll
    for (int j = 0; j < 100; ++j) {
        float a = 0.0f;
#pragma unroll
        for (int i = 0; i < 10; ++i) a += b[i] * tw0[j * 10 + i];
        h[j] = silu_f(a);
    }
    const float* sp = s1 + src * 32;
    const float* vp = v1 + src * 96;
    float* ap = a2 + (size_t)dst * 128;
    for (int c = 0; c < 32; ++c) {
        float w1a = 0, w2a = 0, w3a = 0, w4a = 0, w5a = 0;
        const float* r1 = tW + c * 100;
        const float* r2 = tW + (32 + c) * 100;
        const float* r3 = tW + (64 + c) * 100;
        const float* r4 = tW + (96 + c) * 100;
        const float* r5 = tW + (128 + c) * 100;
#pragma unroll
        for (int j = 0; j < 100; ++j) {
            float hj = h[j];
            w1a += hj * r1[j]; w2a += hj * r2[j]; w3a += hj * r3[j];
            w4a += hj * r4[j]; w5a += hj * r5[j];
        }
        float ssc = sp[c];
        float vx = vp[c], vy = vp[32 + c], vz = vp[64 + c];
        float dotv = vx * csh[0] + vy * csh[1] + vz * csh[2];
        unsafeAtomicAdd(ap + c, w1a * ssc * cs0 + w2a * dotv);
        float cx = vy * csh[2] - vz * csh[1];
        float cy = vz * csh[0] - vx * csh[2];
        float cz = vx * csh[1] - vy * csh[0];
        unsafeAtomicAdd(ap + 32 + c, w3a * ssc * csh[0] + w4a * vx * cs0 + w5a * cx);
        unsafeAtomicAdd(ap + 64 + c, w3a * ssc * csh[1] + w4a * vy * cs0 + w5a * cy);
        unsafeAtomicAdd(ap + 96 + c, w3a * ssc * csh[2] + w4a * vz * cs0 + w5a * cz);
    }
}

__global__ __launch_bounds__(256) void ka_edge3(
    const float* __restrict__ pos, const int* __restrict__ ei,
    const float* __restrict__ eshift, const float* __restrict__ lat,
    const int* __restrict__ batch,
    const float* __restrict__ tw0, const float* __restrict__ w1,
    const float* __restrict__ s2, const float* __restrict__ v2,
    float* __restrict__ a3)
{
    int e = blockIdx.x * 256 + threadIdx.x;
    if (e >= EE) return;
    int src, dst; float cs0, csh[3], b[10];
    edge_features(e, pos, ei, eshift, lat, batch, src, dst, cs0, csh, b);
    float wk[64];
#pragma unroll
    for (int k = 0; k < 64; ++k) wk[k] = 0.0f;
    for (int j = 0; j < 100; ++j) {
        float a = 0.0f;
#pragma unroll
        for (int i = 0; i < 10; ++i) a += b[i] * tw0[j * 10 + i];
        float hj = silu_f(a);
#pragma unroll
        for (int k = 0; k < 64; ++k) wk[k] += hj * w1[j * 64 + k];
    }
    const float* sp = s2 + src * 32;
    const float* vp = v2 + src * 96;
    float* ap = a3 + (size_t)dst * 32;
#pragma unroll
    for (int c = 0; c < 32; ++c) {
        float dotv = vp[c] * csh[0] + vp[32 + c] * csh[1] + vp[64 + c] * csh[2];
        unsafeAtomicAdd(ap + c, wk[c] * sp[c] * cs0 + wk[32 + c] * dotv);
    }
}

// ================= launcher =================
extern "C" void kernel_launch(void* const* d_in, const int* in_sizes, int n_in,
                              void* d_out, int out_size, void* d_ws, size_t ws_size,
                              hipStream_t stream)
{
    const float* pos   = (const float*)d_in[0];
    const float* x     = (const float*)d_in[1];
    const float* z     = (const float*)d_in[2];
    const int*   ei    = (const int*)d_in[3];
    const float* esh   = (const float*)d_in[4];
    const float* lat   = (const float*)d_in[5];
    const int*   batch = (const int*)d_in[6];
    const float* fc1w0 = (const float*)d_in[7];
    const float* fc1w1 = (const float*)d_in[8];
    const float* sc1   = (const float*)d_in[9];
    const float* lin1s = (const float*)d_in[10];
    const float* lin1v = (const float*)d_in[11];
    const float* fc2w0 = (const float*)d_in[12];
    const float* fc2w1 = (const float*)d_in[13];
    const float* sc2s  = (const float*)d_in[14];
    const float* sc2v  = (const float*)d_in[15];
    const float* lin2s = (const float*)d_in[16];
    const float* lin2v = (const float*)d_in[17];
    const float* fcow0 = (const float*)d_in[18];
    const float* fcow1 = (const float*)d_in[19];
    const float* sco   = (const float*)d_in[20];
    const float* lino  = (const float*)d_in[21];
    float* out = (float*)d_out;

    char* cur = (char*)d_ws;
    auto alloc = [&](size_t bytes) { char* r = cur; cur += (bytes + 15) & ~(size_t)15; return r; };

    // a1,a2,a3 contiguous for a single memset
    float* a1  = (float*)alloc((size_t)NN * 64 * 4);
    float* a2  = (float*)alloc((size_t)NN * 128 * 4);
    float* a3  = (float*)alloc((size_t)NN * 32 * 4);
    float* s1  = (float*)alloc((size_t)NN * 32 * 4);
    float* v1  = (float*)alloc((size_t)NN * 96 * 4);
    float* s2  = (float*)alloc((size_t)NN * 32 * 4);
    float* v2  = (float*)alloc((size_t)NN * 96 * 4);
    float* t10 = (float*)alloc(1000 * 4);
    float* t20 = (float*)alloc(1000 * 4);
    float* to0 = (float*)alloc(1000 * 4);
    float* t21 = (float*)alloc(16000 * 4);
    int* deg    = (int*)alloc((size_t)NN * 4);
    int* rowp   = (int*)alloc((size_t)(NN + 4) * 4);
    int* cursor = (int*)alloc((size_t)NN * 4);
    int* bsum   = (int*)alloc(256 * 4);
    int* boff   = (int*)alloc(256 * 4);
    int* gstart = (int*)alloc(68 * 4);
    int* eperm  = (int*)alloc((size_t)EE * 4);
    size_t fixed_need = (size_t)(cur - (char*)d_ws);

    // remaining workspace = msg chunk buffer
    size_t avail = (ws_size > fixed_need + 64) ? (ws_size - fixed_need - 64) : 0;
    unsigned* msg = (unsigned*)cur;

    // chunk capacities in edges (msg bytes/edge: L1=128, L2=256, L3=64)
    size_t capE1 = avail / 128, capE2 = avail / 256, capE3 = avail / 64;
    if (capE1 > EE) capE1 = EE;
    if (capE2 > EE) capE2 = EE;
    if (capE3 > EE) capE3 = EE;

    int nb = NB_N;
    k_prep<<<75, 256, 0, stream>>>(fc1w0, fc2w0, fcow0, fc2w1, t10, t20, to0, t21);
    k_gb<<<nb, 256, 0, stream>>>(batch, gstart);

    if (capE2 >= 16384) {
        // ---- CSR chunked path: no scatter atomics ----
        hipMemsetAsync(deg, 0, (size_t)NN * 4, stream);
        hipMemsetAsync(a1, 0, (size_t)NN * 224 * 4, stream);   // a1,a2,a3
        k_hist <<<NB_E, 256, 0, stream>>>(ei, deg);
        k_scan1<<<nb, 256, 0, stream>>>(deg, bsum);
        k_scan2<<<1, 64, 0, stream>>>(bsum, boff, rowp);
        k_scan3<<<nb, 256, 0, stream>>>(deg, boff, rowp, cursor);
        k_fill <<<NB_E, 256, 0, stream>>>(ei, cursor, eperm);

        // layer 1
        for (int a = 0; a < EE; ) {
            int m = (int)((EE - a < (int)capE1) ? (EE - a) : capE1);
            k_edge1c<<<(m + 255) / 256, 256, 0, stream>>>(a, m, pos, x, ei, esh, lat, batch, eperm, t10, fc1w1, msg);
            k_gatherc<32><<<(NN * 32 + 255) / 256, 256, 0, stream>>>(msg, rowp, a1, a, a + m);
            a += m;
        }
        k_node1<<<nb, 256, 0, stream>>>(x, z, a1, sc1, lin1s, lin1v, s1, v1);

        // layer 2
        for (int a = 0; a < EE; ) {
            int m = (int)((EE - a < (int)capE2) ? (EE - a) : capE2);
            k_edge2c<<<(m + 255) / 256, 256, 0, stream>>>(a, m, pos, ei, esh, lat, batch, eperm, t20, t21, s1, v1, msg);
            k_gatherc<64><<<(NN * 64 + 255) / 256, 256, 0, stream>>>(msg, rowp, a2, a, a + m);
            a += m;
        }
        k_node2<<<nb, 256, 0, stream>>>(z, s1, v1, a2, sc2s, sc2v, lin2s, lin2v, s2, v2);

        // output layer
        for (int a = 0; a < EE; ) {
            int m = (int)((EE - a < (int)capE3) ? (EE - a) : capE3);
            k_edge3c<<<(m + 255) / 256, 256, 0, stream>>>(a, m, pos, ei, esh, lat, batch, eperm, to0, fcow1, s2, v2, msg);
            k_gatherc<16><<<(NN * 16 + 255) / 256, 256, 0, stream>>>(msg, rowp, a3, a, a + m);
            a += m;
        }
        k_out<<<NGRAPHS, 256, 0, stream>>>(z, gstart, s2, a3, sco, lino, out);
    } else {
        // ---- fallback: atomic scatter ----
        hipMemsetAsync(a1, 0, (size_t)NN * 224 * 4, stream);  // a1,a2,a3 contiguous
        ka_edge1<<<NB_E, 256, 0, stream>>>(pos, x, ei, esh, lat, batch, t10, fc1w1, a1);
        k_node1<<<nb, 256, 0, stream>>>(x, z, a1, sc1, lin1s, lin1v, s1, v1);
        ka_edge2<<<NB_E, 256, 0, stream>>>(pos, ei, esh, lat, batch, t20, t21, s1, v1, a2);
        k_node2<<<nb, 256, 0, stream>>>(z, s1, v1, a2, sc2s, sc2v, lin2s, lin2v, s2, v2);
        ka_edge3<<<NB_E, 256, 0, stream>>>(pos, ei, esh, lat, batch, to0, fcow1, s2, v2, a3);
        k_out<<<NGRAPHS, 256, 0, stream>>>(z, gstart, s2, a3, sco, lino, out);
    }
}

// Round 4
// 1068.910 us; speedup vs baseline: 11.6998x; 3.4477x over previous
//
#include <hip/hip_runtime.h>
#include <hip/hip_bf16.h>

#define NN 50000
#define EE 1000000
#define NGRAPHS 64
#define OUTD 100
#define NB_N 196        // (NN+255)/256
#define NB_E 3907       // (EE+255)/256
#define NTAB 2048

#define INV_SQRT_NEIGH 0.22360679774997896f   // 1/sqrt(20)
#define INV_SQRT_NODES 0.035777087639996634f  // 1/sqrt(781.25)
#define SQRT3 1.7320508075688772f
#define BSCALE 2.8234621879136734f            // sqrt(10)/1.12
#define BSTEP 0.3888888888888889f             // 3.5/9
#define INV_BSTEP 2.5714285714285716f
#define PI_F 3.14159265358979323846f
#define TAB_DR (3.5f / 2047.0f)
#define INV_TAB_DR (2047.0f / 3.5f)

__device__ __forceinline__ float silu_f(float x) { return x / (1.0f + __expf(-x)); }
__device__ __forceinline__ float sigm_f(float x) { return 1.0f / (1.0f + __expf(-x)); }

// ---- radial tables: tab[entry][comp] = (silu(basis(r_entry)@w0) @ w1)[comp] ----
// layer1: 32 comps, layer2: 160, layer3: 64. 16 outputs per thread.
__global__ __launch_bounds__(256) void k_table(
    const float* __restrict__ fc1w0, const float* __restrict__ fc1w1,
    const float* __restrict__ fc2w0, const float* __restrict__ fc2w1,
    const float* __restrict__ fcow0, const float* __restrict__ fcow1,
    float* __restrict__ tab1, float* __restrict__ tab2, float* __restrict__ tab3)
{
    int tid = blockIdx.x * 256 + threadIdx.x;
    if (tid >= NTAB * 16) return;
    int entry = tid >> 4, sub = tid & 15;
    float r = entry * TAB_DR;
    float b[10];
#pragma unroll
    for (int i = 0; i < 10; ++i) {
        float d = (r - (float)i * BSTEP) * INV_BSTEP;
        b[i] = __expf(-d * d) * BSCALE;
    }
    const float *w0, *w1p; float* outp; int K, o0;
    if (sub < 2)       { w0 = fc1w0; w1p = fc1w1; K = 32;  o0 = sub * 16;        outp = tab1 + entry * 32; }
    else if (sub < 12) { w0 = fc2w0; w1p = fc2w1; K = 160; o0 = (sub - 2) * 16;  outp = tab2 + entry * 160; }
    else               { w0 = fcow0; w1p = fcow1; K = 64;  o0 = (sub - 12) * 16; outp = tab3 + entry * 64; }
    float acc[16];
#pragma unroll
    for (int t = 0; t < 16; ++t) acc[t] = 0.0f;
    for (int j = 0; j < 100; ++j) {
        float hj = 0.0f;
#pragma unroll
        for (int i = 0; i < 10; ++i) hj += b[i] * w0[i * 100 + j];
        hj = silu_f(hj);
        const float* wr = w1p + j * K + o0;
#pragma unroll
        for (int t = 0; t < 16; ++t) acc[t] += hj * wr[t];
    }
#pragma unroll
    for (int t = 0; t < 16; ++t) outp[o0 + t] = acc[t];
}

// ================= CSR build =================
__global__ __launch_bounds__(256) void k_hist(const int* __restrict__ ei, int* __restrict__ deg)
{
    int e = blockIdx.x * 256 + threadIdx.x;
    if (e < EE) atomicAdd(&deg[ei[EE + e]], 1);
}

__global__ __launch_bounds__(256) void k_scan1(const int* __restrict__ deg, int* __restrict__ bsum)
{
    __shared__ int sd[256];
    int t = threadIdx.x;
    int i = blockIdx.x * 256 + t;
    sd[t] = (i < NN) ? deg[i] : 0;
    __syncthreads();
#pragma unroll
    for (int o = 128; o > 0; o >>= 1) {
        if (t < o) sd[t] += sd[t + o];
        __syncthreads();
    }
    if (t == 0) bsum[blockIdx.x] = sd[0];
}

__global__ void k_scan2(const int* __restrict__ bsum, int* __restrict__ boff, int* __restrict__ rowp)
{
    if (threadIdx.x == 0) {
        int acc = 0;
        for (int b = 0; b < NB_N; ++b) { boff[b] = acc; acc += bsum[b]; }
        rowp[NN] = EE;
    }
}

__global__ __launch_bounds__(256) void k_scan3(
    const int* __restrict__ deg, const int* __restrict__ boff,
    int* __restrict__ rowp, int* __restrict__ cursor)
{
    __shared__ int sd[256];
    int t = threadIdx.x;
    int i = blockIdx.x * 256 + t;
    int v = (i < NN) ? deg[i] : 0;
    sd[t] = v;
    __syncthreads();
#pragma unroll
    for (int o = 1; o < 256; o <<= 1) {
        int xv = 0;
        if (t >= o) xv = sd[t - o];
        __syncthreads();
        sd[t] += xv;
        __syncthreads();
    }
    if (i < NN) {
        int val = boff[blockIdx.x] + sd[t] - v;   // exclusive
        rowp[i] = val;
        cursor[i] = val;
    }
}

// graph boundaries from sorted batch
__global__ __launch_bounds__(256) void k_gb(const int* __restrict__ batch, int* __restrict__ gstart)
{
    int n = blockIdx.x * 256 + threadIdx.x;
    if (n >= NN) return;
    int b = batch[n];
    if (n == 0) { for (int g = 0; g <= b; ++g) gstart[g] = 0; }
    else {
        int pb = batch[n - 1];
        for (int g = pb + 1; g <= b; ++g) gstart[g] = n;
    }
    if (n == NN - 1) { for (int g = b + 1; g <= NGRAPHS; ++g) gstart[g] = NN; }
}

// ---- per-edge geometry once, scattered to dst-sorted slot (24 B/slot) ----
__global__ __launch_bounds__(256) void k_geom(
    const float* __restrict__ pos, const int* __restrict__ ei,
    const float* __restrict__ eshift, const float* __restrict__ lat,
    const int* __restrict__ batch, int* __restrict__ cursor,
    float4* __restrict__ geo4, float2* __restrict__ grs)
{
    int e = blockIdx.x * 256 + threadIdx.x;
    if (e >= EE) return;
    int src = ei[e];
    int dst = ei[EE + e];
    int g = batch[src];
    const float* L = lat + g * 9;
    float t0 = eshift[e*3+0], t1 = eshift[e*3+1], t2 = eshift[e*3+2];
    float vx = pos[dst*3+0] - pos[src*3+0] + t0*L[0] + t1*L[3] + t2*L[6];
    float vy = pos[dst*3+1] - pos[src*3+1] + t0*L[1] + t1*L[4] + t2*L[7];
    float vz = pos[dst*3+2] - pos[src*3+2] + t0*L[2] + t1*L[5] + t2*L[8];
    float r = sqrtf(vx*vx + vy*vy + vz*vz);
    float u = 2.0f * (r * (1.0f/3.5f) - 1.0f);
    float cut;
    if (u > 0.0f) cut = 0.0f;
    else if (u < -2.0f) cut = 1.0f;
    else cut = 0.5f * (1.0f - __cosf(PI_F * u));
    float inv = 1.0f / fmaxf(r, 1e-12f);
    float sc = SQRT3 * cut * inv;
    float t = fminf(r * INV_TAB_DR, 2046.999f);
    int slot = atomicAdd(&cursor[dst], 1);
    geo4[slot] = make_float4(cut, sc * vx, sc * vy, sc * vz);
    grs[slot]  = make_float2(t, __int_as_float(src));
}

// ================= fused node-centric edge kernels (1 wave = 1 dst node) =================
// layer 1: 64 outputs: lane = q*16+c, q=0:ms, q=1..3:mv{x,y,z}, c = channel
__global__ __launch_bounds__(256) void k_fuse1(
    const int* __restrict__ rowp, const float4* __restrict__ geo4,
    const float2* __restrict__ grs, const float* __restrict__ tab1,
    const float* __restrict__ x, float* __restrict__ a1)
{
    int wid = (blockIdx.x * 256 + threadIdx.x) >> 6;
    int l = threadIdx.x & 63;
    if (wid >= NN) return;
    int b0 = rowp[wid], b1 = rowp[wid + 1];
    int q = l >> 4, c = l & 15;
    float acc = 0.0f;
    for (int s = b0; s < b1; ++s) {
        float4 g = geo4[s];
        if (g.x == 0.0f) continue;             // cutoff zero -> all messages zero
        float2 rs = grs[s];
        int i0 = (int)rs.x; float f = rs.x - (float)i0;
        int src = __float_as_int(rs.y);
        const float* T = tab1 + i0 * 32;
        float ws = T[c]      + f * (T[32 + c] - T[c]);
        float wv = T[16 + c] + f * (T[48 + c] - T[16 + c]);
        float xs = x[src * 16 + c];
        float gs = (q == 0) ? g.x : (q == 1 ? g.y : (q == 2 ? g.z : g.w));
        float w  = (q == 0) ? ws : wv;
        acc += w * xs * gs;
    }
    a1[(size_t)wid * 64 + l] = acc;
}

// layer 2: 128 outputs: lane = p*32+c; p=0 accumulates {ms,mx}, p=1 {my,mz}
__global__ __launch_bounds__(256) void k_fuse2(
    const int* __restrict__ rowp, const float4* __restrict__ geo4,
    const float2* __restrict__ grs, const float* __restrict__ tab2,
    const float* __restrict__ s1, const float* __restrict__ v1,
    float* __restrict__ a2)
{
    int wid = (blockIdx.x * 256 + threadIdx.x) >> 6;
    int l = threadIdx.x & 63;
    if (wid >= NN) return;
    int b0 = rowp[wid], b1 = rowp[wid + 1];
    int p = l >> 5, c = l & 31;
    float acc0 = 0.0f, acc1 = 0.0f;
    for (int s = b0; s < b1; ++s) {
        float4 g = geo4[s];
        if (g.x == 0.0f) continue;
        float2 rs = grs[s];
        int i0 = (int)rs.x; float f = rs.x - (float)i0;
        int src = __float_as_int(rs.y);
        const float* T = tab2 + i0 * 160;
        float w1 = T[c]       + f * (T[160 + c]       - T[c]);
        float w2 = T[32 + c]  + f * (T[192 + c]       - T[32 + c]);
        float w3 = T[64 + c]  + f * (T[224 + c]       - T[64 + c]);
        float w4 = T[96 + c]  + f * (T[256 + c]       - T[96 + c]);
        float w5 = T[128 + c] + f * (T[288 + c]       - T[128 + c]);
        float sv = s1[src * 32 + c];
        const float* vp = v1 + (size_t)src * 96;
        float vx = vp[c], vy = vp[32 + c], vz = vp[64 + c];
        float cs0 = g.x, cx = g.y, cy = g.z, cz = g.w;
        float dot = vx * cx + vy * cy + vz * cz;
        float ms = w1 * sv * cs0 + w2 * dot;
        float mx = w3 * sv * cx + w4 * vx * cs0 + w5 * (vy * cz - vz * cy);
        float my = w3 * sv * cy + w4 * vy * cs0 + w5 * (vz * cx - vx * cz);
        float mz = w3 * sv * cz + w4 * vz * cs0 + w5 * (vx * cy - vy * cx);
        acc0 += p ? my : ms;
        acc1 += p ? mz : mx;
    }
    float* ap = a2 + (size_t)wid * 128 + p * 64 + c;
    ap[0]  = acc0;   // p=0: ms[c],  p=1: my[c]
    ap[32] = acc1;   // p=0: mx[c],  p=1: mz[c]
}

// output layer: 32 outputs: lane = p*32+c; halves p process even/odd slots
__global__ __launch_bounds__(256) void k_fuse3(
    const int* __restrict__ rowp, const float4* __restrict__ geo4,
    const float2* __restrict__ grs, const float* __restrict__ tab3,
    const float* __restrict__ s2, const float* __restrict__ v2,
    float* __restrict__ a3)
{
    int wid = (blockIdx.x * 256 + threadIdx.x) >> 6;
    int l = threadIdx.x & 63;
    if (wid >= NN) return;
    int b0 = rowp[wid], b1 = rowp[wid + 1];
    int p = l >> 5, c = l & 31;
    float acc = 0.0f;
    for (int s = b0 + p; s < b1; s += 2) {
        float4 g = geo4[s];
        float2 rs = grs[s];
        int i0 = (int)rs.x; float f = rs.x - (float)i0;
        int src = __float_as_int(rs.y);
        const float* T = tab3 + i0 * 64;
        float w1 = T[c]      + f * (T[64 + c] - T[c]);
        float w2 = T[32 + c] + f * (T[96 + c] - T[32 + c]);
        float sv = s2[src * 32 + c];
        const float* vp = v2 + (size_t)src * 96;
        float dot = vp[c] * g.y + vp[32 + c] * g.z + vp[64 + c] * g.w;
        acc += w1 * sv * g.x + w2 * dot;
    }
    acc += __shfl_xor(acc, 32);
    if (p == 0) a3[(size_t)wid * 32 + c] = acc;
}

// ================= node kernels =================
// a1 layout per node (64 floats): [ms 16][mvx 16][mvy 16][mvz 16]
__global__ __launch_bounds__(256) void k_node1(
    const float* __restrict__ x, const float* __restrict__ z,
    const float* __restrict__ a1,
    const float* __restrict__ sc1, const float* __restrict__ lin1s,
    const float* __restrict__ lin1v,
    float* __restrict__ s1, float* __restrict__ v1)
{
    int n = blockIdx.x * 256 + threadIdx.x;
    if (n >= NN) return;
    float zz = z[n];
    float xs[16], as[16];
#pragma unroll
    for (int c = 0; c < 16; ++c) {
        xs[c] = x[n * 16 + c] * zz;
        as[c] = a1[n * 64 + c] * INV_SQRT_NEIGH;
    }
    float sh[64];
#pragma unroll
    for (int o = 0; o < 64; ++o) sh[o] = 0.0f;
    for (int c = 0; c < 16; ++c) {
        float xc = xs[c], ac = as[c];
#pragma unroll
        for (int o = 0; o < 64; ++o)
            sh[o] += xc * sc1[c * 64 + o] + ac * lin1s[c * 64 + o];
    }
    float gate[32];
#pragma unroll
    for (int o = 0; o < 32; ++o) {
        s1[n * 32 + o] = silu_f(sh[o]);
        gate[o] = sigm_f(sh[32 + o]);
    }
    for (int i = 0; i < 3; ++i) {
        float av[16];
#pragma unroll
        for (int c = 0; c < 16; ++c) av[c] = a1[n * 64 + 16 + i * 16 + c] * INV_SQRT_NEIGH;
        float vh[32];
#pragma unroll
        for (int o = 0; o < 32; ++o) vh[o] = 0.0f;
        for (int c = 0; c < 16; ++c) {
            float ac = av[c];
#pragma unroll
            for (int o = 0; o < 32; ++o) vh[o] += ac * lin1v[c * 32 + o];
        }
#pragma unroll
        for (int o = 0; o < 32; ++o) v1[(n * 3 + i) * 32 + o] = vh[o] * gate[o];
    }
}

// a2 layout per node (128 floats): [ms 32][mvx 32][mvy 32][mvz 32]
__global__ __launch_bounds__(256) void k_node2(
    const float* __restrict__ z,
    const float* __restrict__ s1, const float* __restrict__ v1,
    const float* __restrict__ a2,
    const float* __restrict__ sc2s, const float* __restrict__ sc2v,
    const float* __restrict__ lin2s, const float* __restrict__ lin2v,
    float* __restrict__ s2, float* __restrict__ v2)
{
    int n = blockIdx.x * 256 + threadIdx.x;
    if (n >= NN) return;
    float zz = z[n];
    float sv[32], as[32];
#pragma unroll
    for (int c = 0; c < 32; ++c) {
        sv[c] = s1[n * 32 + c] * zz;
        as[c] = a2[(size_t)n * 128 + c] * INV_SQRT_NEIGH;
    }
    float sh[64];
#pragma unroll
    for (int o = 0; o < 64; ++o) sh[o] = 0.0f;
    for (int c = 0; c < 32; ++c) {
        float a = sv[c], d = as[c];
#pragma unroll
        for (int o = 0; o < 64; ++o)
            sh[o] += a * sc2s[c * 64 + o] + d * lin2s[c * 64 + o];
    }
    float gate[32];
#pragma unroll
    for (int o = 0; o < 32; ++o) {
        s2[n * 32 + o] = silu_f(sh[o]);
        gate[o] = sigm_f(sh[32 + o]);
    }
    for (int i = 0; i < 3; ++i) {
        float vv[32], av[32];
#pragma unroll
        for (int c = 0; c < 32; ++c) {
            vv[c] = v1[(n * 3 + i) * 32 + c];
            av[c] = a2[(size_t)n * 128 + 32 + i * 32 + c] * INV_SQRT_NEIGH;
        }
        float vh[32];
#pragma unroll
        for (int o = 0; o < 32; ++o) vh[o] = 0.0f;
        for (int c = 0; c < 32; ++c) {
            float a = vv[c], d = av[c];
#pragma unroll
            for (int o = 0; o < 32; ++o)
                vh[o] += a * sc2v[c * 32 + o] + d * lin2v[c * 32 + o];
        }
#pragma unroll
        for (int o = 0; o < 32; ++o) v2[(n * 3 + i) * 32 + o] = vh[o] * gate[o];
    }
}

// ---- output: one block per graph, LDS reduction, plain writes ----
__global__ __launch_bounds__(256) void k_out(
    const float* __restrict__ z, const int* __restrict__ gstart,
    const float* __restrict__ s2, const float* __restrict__ a3,
    const float* __restrict__ sco, const float* __restrict__ lino,
    float* __restrict__ out)
{
    __shared__ float red[100];
    int g = blockIdx.x;
    int t = threadIdx.x;
    if (t < 100) red[t] = 0.0f;
    __syncthreads();
    int n0 = gstart[g], n1 = gstart[g + 1];
    float acc[100];
#pragma unroll
    for (int o = 0; o < 100; ++o) acc[o] = 0.0f;
    for (int n = n0 + t; n < n1; n += 256) {
        float zz = z[n];
        for (int c = 0; c < 32; ++c) {
            float a = s2[n * 32 + c] * zz;
            float d = a3[(size_t)n * 32 + c] * INV_SQRT_NEIGH;
#pragma unroll
            for (int o = 0; o < 100; ++o)
                acc[o] += a * sco[c * 100 + o] + d * lino[c * 100 + o];
        }
    }
#pragma unroll
    for (int o = 0; o < 100; ++o) atomicAdd(&red[o], acc[o]);
    __syncthreads();
    if (t < 100) out[g * 100 + t] = red[t] * INV_SQRT_NODES;
}

// ================= launcher =================
extern "C" void kernel_launch(void* const* d_in, const int* in_sizes, int n_in,
                              void* d_out, int out_size, void* d_ws, size_t ws_size,
                              hipStream_t stream)
{
    const float* pos   = (const float*)d_in[0];
    const float* x     = (const float*)d_in[1];
    const float* z     = (const float*)d_in[2];
    const int*   ei    = (const int*)d_in[3];
    const float* esh   = (const float*)d_in[4];
    const float* lat   = (const float*)d_in[5];
    const int*   batch = (const int*)d_in[6];
    const float* fc1w0 = (const float*)d_in[7];
    const float* fc1w1 = (const float*)d_in[8];
    const float* sc1   = (const float*)d_in[9];
    const float* lin1s = (const float*)d_in[10];
    const float* lin1v = (const float*)d_in[11];
    const float* fc2w0 = (const float*)d_in[12];
    const float* fc2w1 = (const float*)d_in[13];
    const float* sc2s  = (const float*)d_in[14];
    const float* sc2v  = (const float*)d_in[15];
    const float* lin2s = (const float*)d_in[16];
    const float* lin2v = (const float*)d_in[17];
    const float* fcow0 = (const float*)d_in[18];
    const float* fcow1 = (const float*)d_in[19];
    const float* sco   = (const float*)d_in[20];
    const float* lino  = (const float*)d_in[21];
    float* out = (float*)d_out;

    char* cur = (char*)d_ws;
    auto alloc = [&](size_t bytes) { char* r = cur; cur += (bytes + 15) & ~(size_t)15; return r; };

    float* a1   = (float*)alloc((size_t)NN * 64 * 4);
    float* a2   = (float*)alloc((size_t)NN * 128 * 4);
    float* a3   = (float*)alloc((size_t)NN * 32 * 4);
    float* s1   = (float*)alloc((size_t)NN * 32 * 4);
    float* v1   = (float*)alloc((size_t)NN * 96 * 4);
    float* s2   = (float*)alloc((size_t)NN * 32 * 4);
    float* v2   = (float*)alloc((size_t)NN * 96 * 4);
    float* tab1 = (float*)alloc((size_t)NTAB * 32 * 4);
    float* tab2 = (float*)alloc((size_t)NTAB * 160 * 4);
    float* tab3 = (float*)alloc((size_t)NTAB * 64 * 4);
    int* deg    = (int*)alloc((size_t)NN * 4);
    int* rowp   = (int*)alloc((size_t)(NN + 4) * 4);
    int* cursor = (int*)alloc((size_t)NN * 4);
    int* bsum   = (int*)alloc(256 * 4);
    int* boff   = (int*)alloc(256 * 4);
    int* gstart = (int*)alloc(68 * 4);
    float4* geo4 = (float4*)alloc((size_t)EE * 16);
    float2* grs  = (float2*)alloc((size_t)EE * 8);

    hipMemsetAsync(deg, 0, (size_t)NN * 4, stream);

    k_table<<<(NTAB * 16) / 256, 256, 0, stream>>>(fc1w0, fc1w1, fc2w0, fc2w1, fcow0, fcow1, tab1, tab2, tab3);
    k_gb<<<NB_N, 256, 0, stream>>>(batch, gstart);

    // CSR + per-edge geometry scattered to dst-sorted slots
    k_hist <<<NB_E, 256, 0, stream>>>(ei, deg);
    k_scan1<<<NB_N, 256, 0, stream>>>(deg, bsum);
    k_scan2<<<1, 64, 0, stream>>>(bsum, boff, rowp);
    k_scan3<<<NB_N, 256, 0, stream>>>(deg, boff, rowp, cursor);
    k_geom <<<NB_E, 256, 0, stream>>>(pos, ei, esh, lat, batch, cursor, geo4, grs);

    int fb = (NN * 64 + 255) / 256;   // 1 wave per node
    k_fuse1<<<fb, 256, 0, stream>>>(rowp, geo4, grs, tab1, x, a1);
    k_node1<<<NB_N, 256, 0, stream>>>(x, z, a1, sc1, lin1s, lin1v, s1, v1);
    k_fuse2<<<fb, 256, 0, stream>>>(rowp, geo4, grs, tab2, s1, v1, a2);
    k_node2<<<NB_N, 256, 0, stream>>>(z, s1, v1, a2, sc2s, sc2v, lin2s, lin2v, s2, v2);
    k_fuse3<<<fb, 256, 0, stream>>>(rowp, geo4, grs, tab3, s2, v2, a3);
    k_out<<<NGRAPHS, 256, 0, stream>>>(z, gstart, s2, a3, sco, lino, out);
}

// Round 5
// 746.564 us; speedup vs baseline: 16.7514x; 1.4318x over previous
//
#include <hip/hip_runtime.h>
#include <hip/hip_bf16.h>

#define NN 50000
#define EE 1000000
#define NGRAPHS 64
#define OUTD 100
#define NB_N 196        // (NN+255)/256
#define NB_E 3907       // (EE+255)/256
#define NTAB 2048
#define SPL 16          // reduction splits per graph

#define INV_SQRT_NEIGH 0.22360679774997896f   // 1/sqrt(20)
#define INV_SQRT_NODES 0.035777087639996634f  // 1/sqrt(781.25)
#define SQRT3 1.7320508075688772f
#define BSCALE 2.8234621879136734f            // sqrt(10)/1.12
#define BSTEP 0.3888888888888889f             // 3.5/9
#define INV_BSTEP 2.5714285714285716f
#define PI_F 3.14159265358979323846f
#define TAB_DR (3.5f / 2047.0f)
#define INV_TAB_DR (2047.0f / 3.5f)

__device__ __forceinline__ float silu_f(float x) { return x / (1.0f + __expf(-x)); }
__device__ __forceinline__ float sigm_f(float x) { return 1.0f / (1.0f + __expf(-x)); }

// ---- radial tables: tab[entry][comp] = (silu(basis(r_entry)@w0) @ w1)[comp] ----
// layer1: 32 comps, layer2: 160, layer3: 64. 16 outputs per thread.
__global__ __launch_bounds__(256) void k_table(
    const float* __restrict__ fc1w0, const float* __restrict__ fc1w1,
    const float* __restrict__ fc2w0, const float* __restrict__ fc2w1,
    const float* __restrict__ fcow0, const float* __restrict__ fcow1,
    float* __restrict__ tab1, float* __restrict__ tab2, float* __restrict__ tab3)
{
    int tid = blockIdx.x * 256 + threadIdx.x;
    if (tid >= NTAB * 16) return;
    int entry = tid >> 4, sub = tid & 15;
    float r = entry * TAB_DR;
    float b[10];
#pragma unroll
    for (int i = 0; i < 10; ++i) {
        float d = (r - (float)i * BSTEP) * INV_BSTEP;
        b[i] = __expf(-d * d) * BSCALE;
    }
    const float *w0, *w1p; float* outp; int K, o0;
    if (sub < 2)       { w0 = fc1w0; w1p = fc1w1; K = 32;  o0 = sub * 16;        outp = tab1 + entry * 32; }
    else if (sub < 12) { w0 = fc2w0; w1p = fc2w1; K = 160; o0 = (sub - 2) * 16;  outp = tab2 + entry * 160; }
    else               { w0 = fcow0; w1p = fcow1; K = 64;  o0 = (sub - 12) * 16; outp = tab3 + entry * 64; }
    float acc[16];
#pragma unroll
    for (int t = 0; t < 16; ++t) acc[t] = 0.0f;
    for (int j = 0; j < 100; ++j) {
        float hj = 0.0f;
#pragma unroll
        for (int i = 0; i < 10; ++i) hj += b[i] * w0[i * 100 + j];
        hj = silu_f(hj);
        const float* wr = w1p + j * K + o0;
#pragma unroll
        for (int t = 0; t < 16; ++t) acc[t] += hj * wr[t];
    }
#pragma unroll
    for (int t = 0; t < 16; ++t) outp[o0 + t] = acc[t];
}

// ================= CSR build =================
__global__ __launch_bounds__(256) void k_hist(const int* __restrict__ ei, int* __restrict__ deg)
{
    int e = blockIdx.x * 256 + threadIdx.x;
    if (e < EE) atomicAdd(&deg[ei[EE + e]], 1);
}

__global__ __launch_bounds__(256) void k_scan1(const int* __restrict__ deg, int* __restrict__ bsum)
{
    __shared__ int sd[256];
    int t = threadIdx.x;
    int i = blockIdx.x * 256 + t;
    sd[t] = (i < NN) ? deg[i] : 0;
    __syncthreads();
#pragma unroll
    for (int o = 128; o > 0; o >>= 1) {
        if (t < o) sd[t] += sd[t + o];
        __syncthreads();
    }
    if (t == 0) bsum[blockIdx.x] = sd[0];
}

__global__ void k_scan2(const int* __restrict__ bsum, int* __restrict__ boff, int* __restrict__ rowp)
{
    if (threadIdx.x == 0) {
        int acc = 0;
        for (int b = 0; b < NB_N; ++b) { boff[b] = acc; acc += bsum[b]; }
        rowp[NN] = EE;
    }
}

__global__ __launch_bounds__(256) void k_scan3(
    const int* __restrict__ deg, const int* __restrict__ boff,
    int* __restrict__ rowp, int* __restrict__ cursor)
{
    __shared__ int sd[256];
    int t = threadIdx.x;
    int i = blockIdx.x * 256 + t;
    int v = (i < NN) ? deg[i] : 0;
    sd[t] = v;
    __syncthreads();
#pragma unroll
    for (int o = 1; o < 256; o <<= 1) {
        int xv = 0;
        if (t >= o) xv = sd[t - o];
        __syncthreads();
        sd[t] += xv;
        __syncthreads();
    }
    if (i < NN) {
        int val = boff[blockIdx.x] + sd[t] - v;   // exclusive
        rowp[i] = val;
        cursor[i] = val;
    }
}

// graph boundaries from sorted batch
__global__ __launch_bounds__(256) void k_gb(const int* __restrict__ batch, int* __restrict__ gstart)
{
    int n = blockIdx.x * 256 + threadIdx.x;
    if (n >= NN) return;
    int b = batch[n];
    if (n == 0) { for (int g = 0; g <= b; ++g) gstart[g] = 0; }
    else {
        int pb = batch[n - 1];
        for (int g = pb + 1; g <= b; ++g) gstart[g] = n;
    }
    if (n == NN - 1) { for (int g = b + 1; g <= NGRAPHS; ++g) gstart[g] = NN; }
}

// ---- per-edge geometry once, scattered to dst-sorted slot (24 B/slot) ----
__global__ __launch_bounds__(256) void k_geom(
    const float* __restrict__ pos, const int* __restrict__ ei,
    const float* __restrict__ eshift, const float* __restrict__ lat,
    const int* __restrict__ batch, int* __restrict__ cursor,
    float4* __restrict__ geo4, float2* __restrict__ grs)
{
    int e = blockIdx.x * 256 + threadIdx.x;
    if (e >= EE) return;
    int src = ei[e];
    int dst = ei[EE + e];
    int g = batch[src];
    const float* L = lat + g * 9;
    float t0 = eshift[e*3+0], t1 = eshift[e*3+1], t2 = eshift[e*3+2];
    float vx = pos[dst*3+0] - pos[src*3+0] + t0*L[0] + t1*L[3] + t2*L[6];
    float vy = pos[dst*3+1] - pos[src*3+1] + t0*L[1] + t1*L[4] + t2*L[7];
    float vz = pos[dst*3+2] - pos[src*3+2] + t0*L[2] + t1*L[5] + t2*L[8];
    float r = sqrtf(vx*vx + vy*vy + vz*vz);
    float u = 2.0f * (r * (1.0f/3.5f) - 1.0f);
    float cut;
    if (u > 0.0f) cut = 0.0f;
    else if (u < -2.0f) cut = 1.0f;
    else cut = 0.5f * (1.0f - __cosf(PI_F * u));
    float inv = 1.0f / fmaxf(r, 1e-12f);
    float sc = SQRT3 * cut * inv;
    float t = fminf(r * INV_TAB_DR, 2046.999f);
    int slot = atomicAdd(&cursor[dst], 1);
    geo4[slot] = make_float4(cut, sc * vx, sc * vy, sc * vz);
    grs[slot]  = make_float2(t, __int_as_float(src));
}

// ================= fused node-centric edge kernels (1 wave = 1 dst node) =================
// layer 1: 64 outputs: lane = q*16+c, q=0:ms, q=1..3:mv{x,y,z}, c = channel
__global__ __launch_bounds__(256) void k_fuse1(
    const int* __restrict__ rowp, const float4* __restrict__ geo4,
    const float2* __restrict__ grs, const float* __restrict__ tab1,
    const float* __restrict__ x, float* __restrict__ a1)
{
    int wid = (blockIdx.x * 256 + threadIdx.x) >> 6;
    int l = threadIdx.x & 63;
    if (wid >= NN) return;
    int b0 = rowp[wid], b1 = rowp[wid + 1];
    int q = l >> 4, c = l & 15;
    float acc = 0.0f;
    for (int s = b0; s < b1; ++s) {
        float4 g = geo4[s];
        if (g.x == 0.0f) continue;             // cutoff zero -> all messages zero
        float2 rs = grs[s];
        int i0 = (int)rs.x; float f = rs.x - (float)i0;
        int src = __float_as_int(rs.y);
        const float* T = tab1 + i0 * 32;
        float ws = T[c]      + f * (T[32 + c] - T[c]);
        float wv = T[16 + c] + f * (T[48 + c] - T[16 + c]);
        float xs = x[src * 16 + c];
        float gs = (q == 0) ? g.x : (q == 1 ? g.y : (q == 2 ? g.z : g.w));
        float w  = (q == 0) ? ws : wv;
        acc += w * xs * gs;
    }
    a1[(size_t)wid * 64 + l] = acc;
}

// layer 2: 128 outputs: lane = p*32+c; p=0 accumulates {ms,mx}, p=1 {my,mz}
__global__ __launch_bounds__(256) void k_fuse2(
    const int* __restrict__ rowp, const float4* __restrict__ geo4,
    const float2* __restrict__ grs, const float* __restrict__ tab2,
    const float* __restrict__ s1, const float* __restrict__ v1,
    float* __restrict__ a2)
{
    int wid = (blockIdx.x * 256 + threadIdx.x) >> 6;
    int l = threadIdx.x & 63;
    if (wid >= NN) return;
    int b0 = rowp[wid], b1 = rowp[wid + 1];
    int p = l >> 5, c = l & 31;
    float acc0 = 0.0f, acc1 = 0.0f;
    for (int s = b0; s < b1; ++s) {
        float4 g = geo4[s];
        if (g.x == 0.0f) continue;
        float2 rs = grs[s];
        int i0 = (int)rs.x; float f = rs.x - (float)i0;
        int src = __float_as_int(rs.y);
        const float* T = tab2 + i0 * 160;
        float w1 = T[c]       + f * (T[160 + c]       - T[c]);
        float w2 = T[32 + c]  + f * (T[192 + c]       - T[32 + c]);
        float w3 = T[64 + c]  + f * (T[224 + c]       - T[64 + c]);
        float w4 = T[96 + c]  + f * (T[256 + c]       - T[96 + c]);
        float w5 = T[128 + c] + f * (T[288 + c]       - T[128 + c]);
        float sv = s1[src * 32 + c];
        const float* vp = v1 + (size_t)src * 96;
        float vx = vp[c], vy = vp[32 + c], vz = vp[64 + c];
        float cs0 = g.x, cx = g.y, cy = g.z, cz = g.w;
        float dot = vx * cx + vy * cy + vz * cz;
        float ms = w1 * sv * cs0 + w2 * dot;
        float mx = w3 * sv * cx + w4 * vx * cs0 + w5 * (vy * cz - vz * cy);
        float my = w3 * sv * cy + w4 * vy * cs0 + w5 * (vz * cx - vx * cz);
        float mz = w3 * sv * cz + w4 * vz * cs0 + w5 * (vx * cy - vy * cx);
        acc0 += p ? my : ms;
        acc1 += p ? mz : mx;
    }
    float* ap = a2 + (size_t)wid * 128 + p * 64 + c;
    ap[0]  = acc0;   // p=0: ms[c],  p=1: my[c]
    ap[32] = acc1;   // p=0: mx[c],  p=1: mz[c]
}

// output layer: 32 outputs: lane = p*32+c; halves p process even/odd slots
__global__ __launch_bounds__(256) void k_fuse3(
    const int* __restrict__ rowp, const float4* __restrict__ geo4,
    const float2* __restrict__ grs, const float* __restrict__ tab3,
    const float* __restrict__ s2, const float* __restrict__ v2,
    float* __restrict__ a3)
{
    int wid = (blockIdx.x * 256 + threadIdx.x) >> 6;
    int l = threadIdx.x & 63;
    if (wid >= NN) return;
    int b0 = rowp[wid], b1 = rowp[wid + 1];
    int p = l >> 5, c = l & 31;
    float acc = 0.0f;
    for (int s = b0 + p; s < b1; s += 2) {
        float4 g = geo4[s];
        float2 rs = grs[s];
        int i0 = (int)rs.x; float f = rs.x - (float)i0;
        int src = __float_as_int(rs.y);
        const float* T = tab3 + i0 * 64;
        float w1 = T[c]      + f * (T[64 + c] - T[c]);
        float w2 = T[32 + c] + f * (T[96 + c] - T[32 + c]);
        float sv = s2[src * 32 + c];
        const float* vp = v2 + (size_t)src * 96;
        float dot = vp[c] * g.y + vp[32 + c] * g.z + vp[64 + c] * g.w;
        acc += w1 * sv * g.x + w2 * dot;
    }
    acc += __shfl_xor(acc, 32);
    if (p == 0) a3[(size_t)wid * 32 + c] = acc;
}

// ================= node kernels =================
// a1 layout per node (64 floats): [ms 16][mvx 16][mvy 16][mvz 16]
__global__ __launch_bounds__(256) void k_node1(
    const float* __restrict__ x, const float* __restrict__ z,
    const float* __restrict__ a1,
    const float* __restrict__ sc1, const float* __restrict__ lin1s,
    const float* __restrict__ lin1v,
    float* __restrict__ s1, float* __restrict__ v1)
{
    int n = blockIdx.x * 256 + threadIdx.x;
    if (n >= NN) return;
    float zz = z[n];
    float xs[16], as[16];
#pragma unroll
    for (int c = 0; c < 16; ++c) {
        xs[c] = x[n * 16 + c] * zz;
        as[c] = a1[n * 64 + c] * INV_SQRT_NEIGH;
    }
    float sh[64];
#pragma unroll
    for (int o = 0; o < 64; ++o) sh[o] = 0.0f;
    for (int c = 0; c < 16; ++c) {
        float xc = xs[c], ac = as[c];
#pragma unroll
        for (int o = 0; o < 64; ++o)
            sh[o] += xc * sc1[c * 64 + o] + ac * lin1s[c * 64 + o];
    }
    float gate[32];
#pragma unroll
    for (int o = 0; o < 32; ++o) {
        s1[n * 32 + o] = silu_f(sh[o]);
        gate[o] = sigm_f(sh[32 + o]);
    }
    for (int i = 0; i < 3; ++i) {
        float av[16];
#pragma unroll
        for (int c = 0; c < 16; ++c) av[c] = a1[n * 64 + 16 + i * 16 + c] * INV_SQRT_NEIGH;
        float vh[32];
#pragma unroll
        for (int o = 0; o < 32; ++o) vh[o] = 0.0f;
        for (int c = 0; c < 16; ++c) {
            float ac = av[c];
#pragma unroll
            for (int o = 0; o < 32; ++o) vh[o] += ac * lin1v[c * 32 + o];
        }
#pragma unroll
        for (int o = 0; o < 32; ++o) v1[(n * 3 + i) * 32 + o] = vh[o] * gate[o];
    }
}

// a2 layout per node (128 floats): [ms 32][mvx 32][mvy 32][mvz 32]
__global__ __launch_bounds__(256) void k_node2(
    const float* __restrict__ z,
    const float* __restrict__ s1, const float* __restrict__ v1,
    const float* __restrict__ a2,
    const float* __restrict__ sc2s, const float* __restrict__ sc2v,
    const float* __restrict__ lin2s, const float* __restrict__ lin2v,
    float* __restrict__ s2, float* __restrict__ v2)
{
    int n = blockIdx.x * 256 + threadIdx.x;
    if (n >= NN) return;
    float zz = z[n];
    float sv[32], as[32];
#pragma unroll
    for (int c = 0; c < 32; ++c) {
        sv[c] = s1[n * 32 + c] * zz;
        as[c] = a2[(size_t)n * 128 + c] * INV_SQRT_NEIGH;
    }
    float sh[64];
#pragma unroll
    for (int o = 0; o < 64; ++o) sh[o] = 0.0f;
    for (int c = 0; c < 32; ++c) {
        float a = sv[c], d = as[c];
#pragma unroll
        for (int o = 0; o < 64; ++o)
            sh[o] += a * sc2s[c * 64 + o] + d * lin2s[c * 64 + o];
    }
    float gate[32];
#pragma unroll
    for (int o = 0; o < 32; ++o) {
        s2[n * 32 + o] = silu_f(sh[o]);
        gate[o] = sigm_f(sh[32 + o]);
    }
    for (int i = 0; i < 3; ++i) {
        float vv[32], av[32];
#pragma unroll
        for (int c = 0; c < 32; ++c) {
            vv[c] = v1[(n * 3 + i) * 32 + c];
            av[c] = a2[(size_t)n * 128 + 32 + i * 32 + c] * INV_SQRT_NEIGH;
        }
        float vh[32];
#pragma unroll
        for (int o = 0; o < 32; ++o) vh[o] = 0.0f;
        for (int c = 0; c < 32; ++c) {
            float a = vv[c], d = av[c];
#pragma unroll
            for (int o = 0; o < 32; ++o)
                vh[o] += a * sc2v[c * 32 + o] + d * lin2v[c * 32 + o];
        }
#pragma unroll
        for (int o = 0; o < 32; ++o) v2[(n * 3 + i) * 32 + o] = vh[o] * gate[o];
    }
}

// ---- output stage 1: per-(graph,split) partial sums of [s2*z | a3] ----
// grid = NGRAPHS*SPL blocks, 256 thr = 64 comps x 4 node-lanes
__global__ __launch_bounds__(256) void k_red(
    const float* __restrict__ z, const int* __restrict__ gstart,
    const float* __restrict__ s2, const float* __restrict__ a3,
    float* __restrict__ pbuf)
{
    int g  = blockIdx.x >> 4;      // / SPL
    int sp = blockIdx.x & (SPL - 1);
    int n0 = gstart[g], n1 = gstart[g + 1];
    int per = (n1 - n0 + SPL - 1) / SPL;
    int a = n0 + sp * per;
    int b = a + per; if (b > n1) b = n1;
    int t = threadIdx.x;
    int comp = t & 63;
    int lane = t >> 6;
    float acc = 0.0f;
    for (int n = a + lane; n < b; n += 4) {
        if (comp < 32) acc += s2[n * 32 + comp] * z[n];
        else           acc += a3[(size_t)n * 32 + (comp - 32)];
    }
    __shared__ float sd[256];
    sd[t] = acc;
    __syncthreads();
    if (t < 64)
        pbuf[(size_t)blockIdx.x * 64 + t] = sd[t] + sd[t + 64] + sd[t + 128] + sd[t + 192];
}

// ---- output stage 2: fold partials + (64,32)@(32,100) GEMM ----
__global__ __launch_bounds__(128) void k_out2(
    const float* __restrict__ pbuf, const float* __restrict__ sco,
    const float* __restrict__ lino, float* __restrict__ out)
{
    __shared__ float A[32], B[32];
    int g = blockIdx.x;
    int t = threadIdx.x;
    if (t < 64) {
        float v = 0.0f;
        for (int sp = 0; sp < SPL; ++sp)
            v += pbuf[(size_t)(g * SPL + sp) * 64 + t];
        if (t < 32) A[t] = v;
        else        B[t - 32] = v * INV_SQRT_NEIGH;
    }
    __syncthreads();
    if (t < 100) {
        float res = 0.0f;
#pragma unroll
        for (int c = 0; c < 32; ++c)
            res += A[c] * sco[c * 100 + t] + B[c] * lino[c * 100 + t];
        out[g * 100 + t] = res * INV_SQRT_NODES;
    }
}

// ================= launcher =================
extern "C" void kernel_launch(void* const* d_in, const int* in_sizes, int n_in,
                              void* d_out, int out_size, void* d_ws, size_t ws_size,
                              hipStream_t stream)
{
    const float* pos   = (const float*)d_in[0];
    const float* x     = (const float*)d_in[1];
    const float* z     = (const float*)d_in[2];
    const int*   ei    = (const int*)d_in[3];
    const float* esh   = (const float*)d_in[4];
    const float* lat   = (const float*)d_in[5];
    const int*   batch = (const int*)d_in[6];
    const float* fc1w0 = (const float*)d_in[7];
    const float* fc1w1 = (const float*)d_in[8];
    const float* sc1   = (const float*)d_in[9];
    const float* lin1s = (const float*)d_in[10];
    const float* lin1v = (const float*)d_in[11];
    const float* fc2w0 = (const float*)d_in[12];
    const float* fc2w1 = (const float*)d_in[13];
    const float* sc2s  = (const float*)d_in[14];
    const float* sc2v  = (const float*)d_in[15];
    const float* lin2s = (const float*)d_in[16];
    const float* lin2v = (const float*)d_in[17];
    const float* fcow0 = (const float*)d_in[18];
    const float* fcow1 = (const float*)d_in[19];
    const float* sco   = (const float*)d_in[20];
    const float* lino  = (const float*)d_in[21];
    float* out = (float*)d_out;

    char* cur = (char*)d_ws;
    auto alloc = [&](size_t bytes) { char* r = cur; cur += (bytes + 15) & ~(size_t)15; return r; };

    float* a1   = (float*)alloc((size_t)NN * 64 * 4);
    float* a2   = (float*)alloc((size_t)NN * 128 * 4);
    float* a3   = (float*)alloc((size_t)NN * 32 * 4);
    float* s1   = (float*)alloc((size_t)NN * 32 * 4);
    float* v1   = (float*)alloc((size_t)NN * 96 * 4);
    float* s2   = (float*)alloc((size_t)NN * 32 * 4);
    float* v2   = (float*)alloc((size_t)NN * 96 * 4);
    float* tab1 = (float*)alloc((size_t)NTAB * 32 * 4);
    float* tab2 = (float*)alloc((size_t)NTAB * 160 * 4);
    float* tab3 = (float*)alloc((size_t)NTAB * 64 * 4);
    float* pbuf = (float*)alloc((size_t)NGRAPHS * SPL * 64 * 4);
    int* deg    = (int*)alloc((size_t)NN * 4);
    int* rowp   = (int*)alloc((size_t)(NN + 4) * 4);
    int* cursor = (int*)alloc((size_t)NN * 4);
    int* bsum   = (int*)alloc(256 * 4);
    int* boff   = (int*)alloc(256 * 4);
    int* gstart = (int*)alloc(68 * 4);
    float4* geo4 = (float4*)alloc((size_t)EE * 16);
    float2* grs  = (float2*)alloc((size_t)EE * 8);

    hipMemsetAsync(deg, 0, (size_t)NN * 4, stream);

    k_table<<<(NTAB * 16) / 256, 256, 0, stream>>>(fc1w0, fc1w1, fc2w0, fc2w1, fcow0, fcow1, tab1, tab2, tab3);
    k_gb<<<NB_N, 256, 0, stream>>>(batch, gstart);

    // CSR + per-edge geometry scattered to dst-sorted slots
    k_hist <<<NB_E, 256, 0, stream>>>(ei, deg);
    k_scan1<<<NB_N, 256, 0, stream>>>(deg, bsum);
    k_scan2<<<1, 64, 0, stream>>>(bsum, boff, rowp);
    k_scan3<<<NB_N, 256, 0, stream>>>(deg, boff, rowp, cursor);
    k_geom <<<NB_E, 256, 0, stream>>>(pos, ei, esh, lat, batch, cursor, geo4, grs);

    int fb = (NN * 64 + 255) / 256;   // 1 wave per node
    k_fuse1<<<fb, 256, 0, stream>>>(rowp, geo4, grs, tab1, x, a1);
    k_node1<<<NB_N, 256, 0, stream>>>(x, z, a1, sc1, lin1s, lin1v, s1, v1);
    k_fuse2<<<fb, 256, 0, stream>>>(rowp, geo4, grs, tab2, s1, v1, a2);
    k_node2<<<NB_N, 256, 0, stream>>>(z, s1, v1, a2, sc2s, sc2v, lin2s, lin2v, s2, v2);
    k_fuse3<<<fb, 256, 0, stream>>>(rowp, geo4, grs, tab3, s2, v2, a3);
    k_red<<<NGRAPHS * SPL, 256, 0, stream>>>(z, gstart, s2, a3, pbuf);
    k_out2<<<NGRAPHS, 128, 0, stream>>>(pbuf, sco, lino, out);
}

// Round 6
// 535.990 us; speedup vs baseline: 23.3326x; 1.3929x over previous
//
#include <hip/hip_runtime.h>
#include <hip/hip_bf16.h>

#define NN 50000
#define EE 1000000
#define NGRAPHS 64
#define OUTD 100
#define NB_N 196        // (NN+255)/256
#define NB_E 3907       // (EE+255)/256
#define NTAB 4096
#define SPL 16          // reduction splits per graph

#define INV_SQRT_NEIGH 0.22360679774997896f   // 1/sqrt(20)
#define INV_SQRT_NODES 0.035777087639996634f  // 1/sqrt(781.25)
#define SQRT3 1.7320508075688772f
#define BSCALE 2.8234621879136734f            // sqrt(10)/1.12
#define BSTEP 0.3888888888888889f             // 3.5/9
#define INV_BSTEP 2.5714285714285716f
#define PI_F 3.14159265358979323846f
#define TAB_DR (3.5f / 4095.0f)
#define TAB_SCALE (4095.0f / 3.5f)

__device__ __forceinline__ float silu_f(float x) { return x / (1.0f + __expf(-x)); }
__device__ __forceinline__ float sigm_f(float x) { return 1.0f / (1.0f + __expf(-x)); }

// ---- radial tables (nearest-neighbor): tab[entry][comp] ----
// layer1: 32 comps, layer2: 160, layer3: 64. 16 outputs per thread.
__global__ __launch_bounds__(256) void k_table(
    const float* __restrict__ fc1w0, const float* __restrict__ fc1w1,
    const float* __restrict__ fc2w0, const float* __restrict__ fc2w1,
    const float* __restrict__ fcow0, const float* __restrict__ fcow1,
    float* __restrict__ tab1, float* __restrict__ tab2, float* __restrict__ tab3)
{
    int tid = blockIdx.x * 256 + threadIdx.x;
    if (tid >= NTAB * 16) return;
    int entry = tid >> 4, sub = tid & 15;
    float r = entry * TAB_DR;
    float b[10];
#pragma unroll
    for (int i = 0; i < 10; ++i) {
        float d = (r - (float)i * BSTEP) * INV_BSTEP;
        b[i] = __expf(-d * d) * BSCALE;
    }
    const float *w0, *w1p; float* outp; int K, o0;
    if (sub < 2)       { w0 = fc1w0; w1p = fc1w1; K = 32;  o0 = sub * 16;        outp = tab1 + (size_t)entry * 32; }
    else if (sub < 12) { w0 = fc2w0; w1p = fc2w1; K = 160; o0 = (sub - 2) * 16;  outp = tab2 + (size_t)entry * 160; }
    else               { w0 = fcow0; w1p = fcow1; K = 64;  o0 = (sub - 12) * 16; outp = tab3 + (size_t)entry * 64; }
    float acc[16];
#pragma unroll
    for (int t = 0; t < 16; ++t) acc[t] = 0.0f;
    for (int j = 0; j < 100; ++j) {
        float hj = 0.0f;
#pragma unroll
        for (int i = 0; i < 10; ++i) hj += b[i] * w0[i * 100 + j];
        hj = silu_f(hj);
        const float* wr = w1p + j * K + o0;
#pragma unroll
        for (int t = 0; t < 16; ++t) acc[t] += hj * wr[t];
    }
#pragma unroll
    for (int t = 0; t < 16; ++t) outp[o0 + t] = acc[t];
}

// ================= CSR build =================
__global__ __launch_bounds__(256) void k_hist(const int* __restrict__ ei, int* __restrict__ deg)
{
    int e = blockIdx.x * 256 + threadIdx.x;
    if (e < EE) atomicAdd(&deg[ei[EE + e]], 1);
}

__global__ __launch_bounds__(256) void k_scan1(const int* __restrict__ deg, int* __restrict__ bsum)
{
    __shared__ int sd[256];
    int t = threadIdx.x;
    int i = blockIdx.x * 256 + t;
    sd[t] = (i < NN) ? deg[i] : 0;
    __syncthreads();
#pragma unroll
    for (int o = 128; o > 0; o >>= 1) {
        if (t < o) sd[t] += sd[t + o];
        __syncthreads();
    }
    if (t == 0) bsum[blockIdx.x] = sd[0];
}

__global__ void k_scan2(const int* __restrict__ bsum, int* __restrict__ boff, int* __restrict__ rowp)
{
    if (threadIdx.x == 0) {
        int acc = 0;
        for (int b = 0; b < NB_N; ++b) { boff[b] = acc; acc += bsum[b]; }
        rowp[NN] = EE;
    }
}

__global__ __launch_bounds__(256) void k_scan3(
    const int* __restrict__ deg, const int* __restrict__ boff,
    int* __restrict__ rowp, int* __restrict__ cursor)
{
    __shared__ int sd[256];
    int t = threadIdx.x;
    int i = blockIdx.x * 256 + t;
    int v = (i < NN) ? deg[i] : 0;
    sd[t] = v;
    __syncthreads();
#pragma unroll
    for (int o = 1; o < 256; o <<= 1) {
        int xv = 0;
        if (t >= o) xv = sd[t - o];
        __syncthreads();
        sd[t] += xv;
        __syncthreads();
    }
    if (i < NN) {
        int val = boff[blockIdx.x] + sd[t] - v;   // exclusive
        rowp[i] = val;
        cursor[i] = val;
    }
}

// graph boundaries from sorted batch
__global__ __launch_bounds__(256) void k_gb(const int* __restrict__ batch, int* __restrict__ gstart)
{
    int n = blockIdx.x * 256 + threadIdx.x;
    if (n >= NN) return;
    int b = batch[n];
    if (n == 0) { for (int g = 0; g <= b; ++g) gstart[g] = 0; }
    else {
        int pb = batch[n - 1];
        for (int g = pb + 1; g <= b; ++g) gstart[g] = n;
    }
    if (n == NN - 1) { for (int g = b + 1; g <= NGRAPHS; ++g) gstart[g] = NN; }
}

// ---- per-edge geometry once, scattered to dst-sorted slot (24 B/slot) ----
// grs.x = pre-rounded nearest table index (+0.5 applied here)
__global__ __launch_bounds__(256) void k_geom(
    const float* __restrict__ pos, const int* __restrict__ ei,
    const float* __restrict__ eshift, const float* __restrict__ lat,
    const int* __restrict__ batch, int* __restrict__ cursor,
    float4* __restrict__ geo4, float2* __restrict__ grs)
{
    int e = blockIdx.x * 256 + threadIdx.x;
    if (e >= EE) return;
    int src = ei[e];
    int dst = ei[EE + e];
    int g = batch[src];
    const float* L = lat + g * 9;
    float t0 = eshift[e*3+0], t1 = eshift[e*3+1], t2 = eshift[e*3+2];
    float vx = pos[dst*3+0] - pos[src*3+0] + t0*L[0] + t1*L[3] + t2*L[6];
    float vy = pos[dst*3+1] - pos[src*3+1] + t0*L[1] + t1*L[4] + t2*L[7];
    float vz = pos[dst*3+2] - pos[src*3+2] + t0*L[2] + t1*L[5] + t2*L[8];
    float r = sqrtf(vx*vx + vy*vy + vz*vz);
    float u = 2.0f * (r * (1.0f/3.5f) - 1.0f);
    float cut;
    if (u > 0.0f) cut = 0.0f;
    else if (u < -2.0f) cut = 1.0f;
    else cut = 0.5f * (1.0f - __cosf(PI_F * u));
    float inv = 1.0f / fmaxf(r, 1e-12f);
    float sc = SQRT3 * cut * inv;
    float t = fminf(r * TAB_SCALE + 0.5f, 4095.0f);
    int slot = atomicAdd(&cursor[dst], 1);
    geo4[slot] = make_float4(cut, sc * vx, sc * vy, sc * vz);
    grs[slot]  = make_float2(t, __int_as_float(src));
}

// ================= fused node-centric edge kernels (1 wave = 1 dst node) =================
// layer 1: 64 outputs: lane = q*16+c, q=0:ms, q=1..3:mv{x,y,z}; 4-edge unroll
#define F1_EDGE(G, R, ACC) {                                        \
    int i0_ = (int)(R).x;                                           \
    int src_ = __float_as_int((R).y);                               \
    float w_ = tab1[(size_t)i0_ * 32 + toff];                       \
    float xs_ = x[src_ * 16 + c];                                   \
    float gs_ = (q == 0) ? (G).x : (q == 1 ? (G).y : (q == 2 ? (G).z : (G).w)); \
    ACC += w_ * xs_ * gs_; }

__global__ __launch_bounds__(256) void k_fuse1(
    const int* __restrict__ rowp, const float4* __restrict__ geo4,
    const float2* __restrict__ grs, const float* __restrict__ tab1,
    const float* __restrict__ x, float* __restrict__ a1)
{
    int wid = (blockIdx.x * 256 + threadIdx.x) >> 6;
    int l = threadIdx.x & 63;
    if (wid >= NN) return;
    int b0 = __builtin_amdgcn_readfirstlane(rowp[wid]);
    int b1 = __builtin_amdgcn_readfirstlane(rowp[wid + 1]);
    int q = l >> 4, c = l & 15;
    int toff = (q ? 16 : 0) + c;
    float aA = 0.0f, aB = 0.0f, aC = 0.0f, aD = 0.0f;
    int s = b0;
    for (; s + 3 < b1; s += 4) {
        float4 gA = geo4[s], gB = geo4[s+1], gC = geo4[s+2], gD = geo4[s+3];
        float2 rA = grs[s],  rB = grs[s+1],  rC = grs[s+2],  rD = grs[s+3];
        F1_EDGE(gA, rA, aA) F1_EDGE(gB, rB, aB)
        F1_EDGE(gC, rC, aC) F1_EDGE(gD, rD, aD)
    }
    for (; s < b1; ++s) {
        float4 gA = geo4[s]; float2 rA = grs[s];
        F1_EDGE(gA, rA, aA)
    }
    a1[(size_t)wid * 64 + l] = (aA + aB) + (aC + aD);
}

// layer 2: lane = p*32+c; p=0 accumulates {ms,mx}, p=1 {my,mz}; 3-edge unroll
#define F2_EDGE(G, R, A0, A1) {                                     \
    int i0_ = (int)(R).x;                                           \
    int src_ = __float_as_int((R).y);                               \
    const float* T_ = tab2 + (size_t)i0_ * 160;                     \
    float w1_ = T_[c], w2_ = T_[32 + c], w3_ = T_[64 + c];          \
    float w4_ = T_[96 + c], w5_ = T_[128 + c];                      \
    float sv_ = s1[src_ * 32 + c];                                  \
    const float* vp_ = v1 + (size_t)src_ * 96;                      \
    float vx_ = vp_[c], vy_ = vp_[32 + c], vz_ = vp_[64 + c];       \
    float cs_ = (G).x, cx_ = (G).y, cy_ = (G).z, cz_ = (G).w;       \
    float dot_ = vx_ * cx_ + vy_ * cy_ + vz_ * cz_;                 \
    float ms_ = w1_ * sv_ * cs_ + w2_ * dot_;                       \
    float mx_ = w3_ * sv_ * cx_ + w4_ * vx_ * cs_ + w5_ * (vy_ * cz_ - vz_ * cy_); \
    float my_ = w3_ * sv_ * cy_ + w4_ * vy_ * cs_ + w5_ * (vz_ * cx_ - vx_ * cz_); \
    float mz_ = w3_ * sv_ * cz_ + w4_ * vz_ * cs_ + w5_ * (vx_ * cy_ - vy_ * cx_); \
    A0 += p ? my_ : ms_;                                            \
    A1 += p ? mz_ : mx_; }

__global__ __launch_bounds__(256) void k_fuse2(
    const int* __restrict__ rowp, const float4* __restrict__ geo4,
    const float2* __restrict__ grs, const float* __restrict__ tab2,
    const float* __restrict__ s1, const float* __restrict__ v1,
    float* __restrict__ a2)
{
    int wid = (blockIdx.x * 256 + threadIdx.x) >> 6;
    int l = threadIdx.x & 63;
    if (wid >= NN) return;
    int b0 = __builtin_amdgcn_readfirstlane(rowp[wid]);
    int b1 = __builtin_amdgcn_readfirstlane(rowp[wid + 1]);
    int p = l >> 5, c = l & 31;
    float a0A = 0, a1A = 0, a0B = 0, a1B = 0, a0C = 0, a1C = 0;
    int s = b0;
    for (; s + 2 < b1; s += 3) {
        float4 gA = geo4[s], gB = geo4[s+1], gC = geo4[s+2];
        float2 rA = grs[s],  rB = grs[s+1],  rC = grs[s+2];
        F2_EDGE(gA, rA, a0A, a1A)
        F2_EDGE(gB, rB, a0B, a1B)
        F2_EDGE(gC, rC, a0C, a1C)
    }
    for (; s < b1; ++s) {
        float4 gA = geo4[s]; float2 rA = grs[s];
        F2_EDGE(gA, rA, a0A, a1A)
    }
    float acc0 = a0A + a0B + a0C;
    float acc1 = a1A + a1B + a1C;
    float* ap = a2 + (size_t)wid * 128 + p * 64 + c;
    ap[0]  = acc0;   // p=0: ms[c],  p=1: my[c]
    ap[32] = acc1;   // p=0: mx[c],  p=1: mz[c]
}

// output layer: lane = p*32+c; halves process even/odd slots; 2-edge unroll per half
#define F3_EDGE(G, R, ACC) {                                        \
    int i0_ = (int)(R).x;                                           \
    int src_ = __float_as_int((R).y);                               \
    const float* T_ = tab3 + (size_t)i0_ * 64;                      \
    float w1_ = T_[c], w2_ = T_[32 + c];                            \
    float sv_ = s2[src_ * 32 + c];                                  \
    const float* vp_ = v2 + (size_t)src_ * 96;                      \
    float dot_ = vp_[c] * (G).y + vp_[32 + c] * (G).z + vp_[64 + c] * (G).w; \
    ACC += w1_ * sv_ * (G).x + w2_ * dot_; }

__global__ __launch_bounds__(256) void k_fuse3(
    const int* __restrict__ rowp, const float4* __restrict__ geo4,
    const float2* __restrict__ grs, const float* __restrict__ tab3,
    const float* __restrict__ s2, const float* __restrict__ v2,
    float* __restrict__ a3)
{
    int wid = (blockIdx.x * 256 + threadIdx.x) >> 6;
    int l = threadIdx.x & 63;
    if (wid >= NN) return;
    int b0 = __builtin_amdgcn_readfirstlane(rowp[wid]);
    int b1 = __builtin_amdgcn_readfirstlane(rowp[wid + 1]);
    int p = l >> 5, c = l & 31;
    float aA = 0.0f, aB = 0.0f;
    int s = b0 + p;
    for (; s + 2 < b1; s += 4) {
        float4 gA = geo4[s], gB = geo4[s+2];
        float2 rA = grs[s],  rB = grs[s+2];
        F3_EDGE(gA, rA, aA)
        F3_EDGE(gB, rB, aB)
    }
    for (; s < b1; s += 2) {
        float4 gA = geo4[s]; float2 rA = grs[s];
        F3_EDGE(gA, rA, aA)
    }
    float acc = aA + aB;
    acc += __shfl_xor(acc, 32);
    if (p == 0) a3[(size_t)wid * 32 + c] = acc;
}

// ================= node kernels =================
// a1 layout per node (64 floats): [ms 16][mvx 16][mvy 16][mvz 16]
__global__ __launch_bounds__(256) void k_node1(
    const float* __restrict__ x, const float* __restrict__ z,
    const float* __restrict__ a1,
    const float* __restrict__ sc1, const float* __restrict__ lin1s,
    const float* __restrict__ lin1v,
    float* __restrict__ s1, float* __restrict__ v1)
{
    int n = blockIdx.x * 256 + threadIdx.x;
    if (n >= NN) return;
    float zz = z[n];
    float xs[16], as[16];
#pragma unroll
    for (int c = 0; c < 16; ++c) {
        xs[c] = x[n * 16 + c] * zz;
        as[c] = a1[n * 64 + c] * INV_SQRT_NEIGH;
    }
    float sh[64];
#pragma unroll
    for (int o = 0; o < 64; ++o) sh[o] = 0.0f;
    for (int c = 0; c < 16; ++c) {
        float xc = xs[c], ac = as[c];
#pragma unroll
        for (int o = 0; o < 64; ++o)
            sh[o] += xc * sc1[c * 64 + o] + ac * lin1s[c * 64 + o];
    }
    float gate[32];
#pragma unroll
    for (int o = 0; o < 32; ++o) {
        s1[n * 32 + o] = silu_f(sh[o]);
        gate[o] = sigm_f(sh[32 + o]);
    }
    for (int i = 0; i < 3; ++i) {
        float av[16];
#pragma unroll
        for (int c = 0; c < 16; ++c) av[c] = a1[n * 64 + 16 + i * 16 + c] * INV_SQRT_NEIGH;
        float vh[32];
#pragma unroll
        for (int o = 0; o < 32; ++o) vh[o] = 0.0f;
        for (int c = 0; c < 16; ++c) {
            float ac = av[c];
#pragma unroll
            for (int o = 0; o < 32; ++o) vh[o] += ac * lin1v[c * 32 + o];
        }
#pragma unroll
        for (int o = 0; o < 32; ++o) v1[(n * 3 + i) * 32 + o] = vh[o] * gate[o];
    }
}

// a2 layout per node (128 floats): [ms 32][mvx 32][mvy 32][mvz 32]
__global__ __launch_bounds__(256) void k_node2(
    const float* __restrict__ z,
    const float* __restrict__ s1, const float* __restrict__ v1,
    const float* __restrict__ a2,
    const float* __restrict__ sc2s, const float* __restrict__ sc2v,
    const float* __restrict__ lin2s, const float* __restrict__ lin2v,
    float* __restrict__ s2, float* __restrict__ v2)
{
    int n = blockIdx.x * 256 + threadIdx.x;
    if (n >= NN) return;
    float zz = z[n];
    float sv[32], as[32];
#pragma unroll
    for (int c = 0; c < 32; ++c) {
        sv[c] = s1[n * 32 + c] * zz;
        as[c] = a2[(size_t)n * 128 + c] * INV_SQRT_NEIGH;
    }
    float sh[64];
#pragma unroll
    for (int o = 0; o < 64; ++o) sh[o] = 0.0f;
    for (int c = 0; c < 32; ++c) {
        float a = sv[c], d = as[c];
#pragma unroll
        for (int o = 0; o < 64; ++o)
            sh[o] += a * sc2s[c * 64 + o] + d * lin2s[c * 64 + o];
    }
    float gate[32];
#pragma unroll
    for (int o = 0; o < 32; ++o) {
        s2[n * 32 + o] = silu_f(sh[o]);
        gate[o] = sigm_f(sh[32 + o]);
    }
    for (int i = 0; i < 3; ++i) {
        float vv[32], av[32];
#pragma unroll
        for (int c = 0; c < 32; ++c) {
            vv[c] = v1[(n * 3 + i) * 32 + c];
            av[c] = a2[(size_t)n * 128 + 32 + i * 32 + c] * INV_SQRT_NEIGH;
        }
        float vh[32];
#pragma unroll
        for (int o = 0; o < 32; ++o) vh[o] = 0.0f;
        for (int c = 0; c < 32; ++c) {
            float a = vv[c], d = av[c];
#pragma unroll
            for (int o = 0; o < 32; ++o)
                vh[o] += a * sc2v[c * 32 + o] + d * lin2v[c * 32 + o];
        }
#pragma unroll
        for (int o = 0; o < 32; ++o) v2[(n * 3 + i) * 32 + o] = vh[o] * gate[o];
    }
}

// ---- output stage 1: per-(graph,split) partial sums of [s2*z | a3] ----
__global__ __launch_bounds__(256) void k_red(
    const float* __restrict__ z, const int* __restrict__ gstart,
    const float* __restrict__ s2, const float* __restrict__ a3,
    float* __restrict__ pbuf)
{
    int g  = blockIdx.x >> 4;      // / SPL
    int sp = blockIdx.x & (SPL - 1);
    int n0 = gstart[g], n1 = gstart[g + 1];
    int per = (n1 - n0 + SPL - 1) / SPL;
    int a = n0 + sp * per;
    int b = a + per; if (b > n1) b = n1;
    int t = threadIdx.x;
    int comp = t & 63;
    int lane = t >> 6;
    float acc = 0.0f;
    for (int n = a + lane; n < b; n += 4) {
        if (comp < 32) acc += s2[n * 32 + comp] * z[n];
        else           acc += a3[(size_t)n * 32 + (comp - 32)];
    }
    __shared__ float sd[256];
    sd[t] = acc;
    __syncthreads();
    if (t < 64)
        pbuf[(size_t)blockIdx.x * 64 + t] = sd[t] + sd[t + 64] + sd[t + 128] + sd[t + 192];
}

// ---- output stage 2: fold partials + (64,32)@(32,100) GEMM ----
__global__ __launch_bounds__(128) void k_out2(
    const float* __restrict__ pbuf, const float* __restrict__ sco,
    const float* __restrict__ lino, float* __restrict__ out)
{
    __shared__ float A[32], B[32];
    int g = blockIdx.x;
    int t = threadIdx.x;
    if (t < 64) {
        float v = 0.0f;
        for (int sp = 0; sp < SPL; ++sp)
            v += pbuf[(size_t)(g * SPL + sp) * 64 + t];
        if (t < 32) A[t] = v;
        else        B[t - 32] = v * INV_SQRT_NEIGH;
    }
    __syncthreads();
    if (t < 100) {
        float res = 0.0f;
#pragma unroll
        for (int c = 0; c < 32; ++c)
            res += A[c] * sco[c * 100 + t] + B[c] * lino[c * 100 + t];
        out[g * 100 + t] = res * INV_SQRT_NODES;
    }
}

// ================= launcher =================
extern "C" void kernel_launch(void* const* d_in, const int* in_sizes, int n_in,
                              void* d_out, int out_size, void* d_ws, size_t ws_size,
                              hipStream_t stream)
{
    const float* pos   = (const float*)d_in[0];
    const float* x     = (const float*)d_in[1];
    const float* z     = (const float*)d_in[2];
    const int*   ei    = (const int*)d_in[3];
    const float* esh   = (const float*)d_in[4];
    const float* lat   = (const float*)d_in[5];
    const int*   batch = (const int*)d_in[6];
    const float* fc1w0 = (const float*)d_in[7];
    const float* fc1w1 = (const float*)d_in[8];
    const float* sc1   = (const float*)d_in[9];
    const float* lin1s = (const float*)d_in[10];
    const float* lin1v = (const float*)d_in[11];
    const float* fc2w0 = (const float*)d_in[12];
    const float* fc2w1 = (const float*)d_in[13];
    const float* sc2s  = (const float*)d_in[14];
    const float* sc2v  = (const float*)d_in[15];
    const float* lin2s = (const float*)d_in[16];
    const float* lin2v = (const float*)d_in[17];
    const float* fcow0 = (const float*)d_in[18];
    const float* fcow1 = (const float*)d_in[19];
    const float* sco   = (const float*)d_in[20];
    const float* lino  = (const float*)d_in[21];
    float* out = (float*)d_out;

    char* cur = (char*)d_ws;
    auto alloc = [&](size_t bytes) { char* r = cur; cur += (bytes + 15) & ~(size_t)15; return r; };

    float* a1   = (float*)alloc((size_t)NN * 64 * 4);
    float* a2   = (float*)alloc((size_t)NN * 128 * 4);
    float* a3   = (float*)alloc((size_t)NN * 32 * 4);
    float* s1   = (float*)alloc((size_t)NN * 32 * 4);
    float* v1   = (float*)alloc((size_t)NN * 96 * 4);
    float* s2   = (float*)alloc((size_t)NN * 32 * 4);
    float* v2   = (float*)alloc((size_t)NN * 96 * 4);
    float* tab1 = (float*)alloc((size_t)NTAB * 32 * 4);
    float* tab2 = (float*)alloc((size_t)NTAB * 160 * 4);
    float* tab3 = (float*)alloc((size_t)NTAB * 64 * 4);
    float* pbuf = (float*)alloc((size_t)NGRAPHS * SPL * 64 * 4);
    int* deg    = (int*)alloc((size_t)NN * 4);
    int* rowp   = (int*)alloc((size_t)(NN + 4) * 4);
    int* cursor = (int*)alloc((size_t)NN * 4);
    int* bsum   = (int*)alloc(256 * 4);
    int* boff   = (int*)alloc(256 * 4);
    int* gstart = (int*)alloc(68 * 4);
    float4* geo4 = (float4*)alloc((size_t)EE * 16);
    float2* grs  = (float2*)alloc((size_t)EE * 8);

    hipMemsetAsync(deg, 0, (size_t)NN * 4, stream);

    k_table<<<(NTAB * 16) / 256, 256, 0, stream>>>(fc1w0, fc1w1, fc2w0, fc2w1, fcow0, fcow1, tab1, tab2, tab3);
    k_gb<<<NB_N, 256, 0, stream>>>(batch, gstart);

    // CSR + per-edge geometry scattered to dst-sorted slots
    k_hist <<<NB_E, 256, 0, stream>>>(ei, deg);
    k_scan1<<<NB_N, 256, 0, stream>>>(deg, bsum);
    k_scan2<<<1, 64, 0, stream>>>(bsum, boff, rowp);
    k_scan3<<<NB_N, 256, 0, stream>>>(deg, boff, rowp, cursor);
    k_geom <<<NB_E, 256, 0, stream>>>(pos, ei, esh, lat, batch, cursor, geo4, grs);

    int fb = (NN * 64 + 255) / 256;   // 1 wave per node
    k_fuse1<<<fb, 256, 0, stream>>>(rowp, geo4, grs, tab1, x, a1);
    k_node1<<<NB_N, 256, 0, stream>>>(x, z, a1, sc1, lin1s, lin1v, s1, v1);
    k_fuse2<<<fb, 256, 0, stream>>>(rowp, geo4, grs, tab2, s1, v1, a2);
    k_node2<<<NB_N, 256, 0, stream>>>(z, s1, v1, a2, sc2s, sc2v, lin2s, lin2v, s2, v2);
    k_fuse3<<<fb, 256, 0, stream>>>(rowp, geo4, grs, tab3, s2, v2, a3);
    k_red<<<NGRAPHS * SPL, 256, 0, stream>>>(z, gstart, s2, a3, pbuf);
    k_out2<<<NGRAPHS, 128, 0, stream>>>(pbuf, sco, lino, out);
}

// Round 8
// 492.669 us; speedup vs baseline: 25.3843x; 1.0879x over previous
//
#include <hip/hip_runtime.h>
#include <hip/hip_bf16.h>

#define NN 50000
#define EE 1000000
#define NGRAPHS 64
#define OUTD 100
#define NB_N 196        // (NN+255)/256
#define NB_E 3907       // (EE+255)/256
#define NTAB 4096
#define SPL 16          // reduction splits per graph

#define INV_SQRT_NEIGH 0.22360679774997896f   // 1/sqrt(20)
#define INV_SQRT_NODES 0.035777087639996634f  // 1/sqrt(781.25)
#define SQRT3 1.7320508075688772f
#define BSCALE 2.8234621879136734f            // sqrt(10)/1.12
#define BSTEP 0.3888888888888889f             // 3.5/9
#define INV_BSTEP 2.5714285714285716f
#define PI_F 3.14159265358979323846f
#define TAB_DR (3.5f / 4095.0f)
#define TAB_SCALE (4095.0f / 3.5f)

__device__ __forceinline__ float silu_f(float x) { return x / (1.0f + __expf(-x)); }
__device__ __forceinline__ float sigm_f(float x) { return 1.0f / (1.0f + __expf(-x)); }

__device__ __forceinline__ unsigned short f2bf(float f) {
    union { float f; unsigned u; } v; v.f = f;
    unsigned r = v.u + 0x7fffu + ((v.u >> 16) & 1u);
    return (unsigned short)(r >> 16);
}
__device__ __forceinline__ float bf2f(unsigned short u) {
    return __uint_as_float((unsigned)u << 16);
}

// ================= combined prologue: radial tables + graph bounds + degree hist =================
// blocks [0,256): tables; [256,452): graph bounds; [452,4359): histogram
__global__ __launch_bounds__(256) void k_pre(
    const float* __restrict__ fc1w0, const float* __restrict__ fc1w1,
    const float* __restrict__ fc2w0, const float* __restrict__ fc2w1,
    const float* __restrict__ fcow0, const float* __restrict__ fcow1,
    float* __restrict__ tab1, float* __restrict__ tab2, float* __restrict__ tab3,
    const int* __restrict__ batch, int* __restrict__ gstart,
    const int* __restrict__ ei, int* __restrict__ deg)
{
    int blk = blockIdx.x;
    if (blk < 256) {
        int tid = blk * 256 + threadIdx.x;   // < NTAB*16
        int entry = tid >> 4, sub = tid & 15;
        float r = entry * TAB_DR;
        float b[10];
#pragma unroll
        for (int i = 0; i < 10; ++i) {
            float d = (r - (float)i * BSTEP) * INV_BSTEP;
            b[i] = __expf(-d * d) * BSCALE;
        }
        const float *w0, *w1p; float* outp; int K, o0;
        if (sub < 2)       { w0 = fc1w0; w1p = fc1w1; K = 32;  o0 = sub * 16;        outp = tab1 + (size_t)entry * 32; }
        else if (sub < 12) { w0 = fc2w0; w1p = fc2w1; K = 160; o0 = (sub - 2) * 16;  outp = tab2 + (size_t)entry * 160; }
        else               { w0 = fcow0; w1p = fcow1; K = 64;  o0 = (sub - 12) * 16; outp = tab3 + (size_t)entry * 64; }
        float acc[16];
#pragma unroll
        for (int t = 0; t < 16; ++t) acc[t] = 0.0f;
        for (int j = 0; j < 100; ++j) {
            float hj = 0.0f;
#pragma unroll
            for (int i = 0; i < 10; ++i) hj += b[i] * w0[i * 100 + j];
            hj = silu_f(hj);
            const float* wr = w1p + j * K + o0;
#pragma unroll
            for (int t = 0; t < 16; ++t) acc[t] += hj * wr[t];
        }
#pragma unroll
        for (int t = 0; t < 16; ++t) outp[o0 + t] = acc[t];
    } else if (blk < 256 + NB_N) {
        int n = (blk - 256) * 256 + threadIdx.x;
        if (n >= NN) return;
        int b = batch[n];
        if (n == 0) { for (int g = 0; g <= b; ++g) gstart[g] = 0; }
        else {
            int pb = batch[n - 1];
            for (int g = pb + 1; g <= b; ++g) gstart[g] = n;
        }
        if (n == NN - 1) { for (int g = b + 1; g <= NGRAPHS; ++g) gstart[g] = NN; }
    } else {
        int e = (blk - 256 - NB_N) * 256 + threadIdx.x;
        if (e < EE) atomicAdd(&deg[ei[EE + e]], 1);
    }
}

// ================= CSR scans =================
__global__ __launch_bounds__(256) void k_scan1(const int* __restrict__ deg, int* __restrict__ bsum)
{
    __shared__ int sd[256];
    int t = threadIdx.x;
    int i = blockIdx.x * 256 + t;
    sd[t] = (i < NN) ? deg[i] : 0;
    __syncthreads();
#pragma unroll
    for (int o = 128; o > 0; o >>= 1) {
        if (t < o) sd[t] += sd[t + o];
        __syncthreads();
    }
    if (t == 0) bsum[blockIdx.x] = sd[0];
}

__global__ void k_scan2(const int* __restrict__ bsum, int* __restrict__ boff, int* __restrict__ rowp)
{
    if (threadIdx.x == 0) {
        int acc = 0;
        for (int b = 0; b < NB_N; ++b) { boff[b] = acc; acc += bsum[b]; }
        rowp[NN] = EE;
    }
}

__global__ __launch_bounds__(256) void k_scan3(
    const int* __restrict__ deg, const int* __restrict__ boff,
    int* __restrict__ rowp, int* __restrict__ cursor)
{
    __shared__ int sd[256];
    int t = threadIdx.x;
    int i = blockIdx.x * 256 + t;
    int v = (i < NN) ? deg[i] : 0;
    sd[t] = v;
    __syncthreads();
#pragma unroll
    for (int o = 1; o < 256; o <<= 1) {
        int xv = 0;
        if (t >= o) xv = sd[t - o];
        __syncthreads();
        sd[t] += xv;
        __syncthreads();
    }
    if (i < NN) {
        int val = boff[blockIdx.x] + sd[t] - v;   // exclusive
        rowp[i] = val;
        cursor[i] = val;
    }
}

// ---- per-edge geometry once, scattered to dst-sorted slot (24 B/slot) ----
__global__ __launch_bounds__(256) void k_geom(
    const float* __restrict__ pos, const int* __restrict__ ei,
    const float* __restrict__ eshift, const float* __restrict__ lat,
    const int* __restrict__ batch, int* __restrict__ cursor,
    float4* __restrict__ geo4, float2* __restrict__ grs)
{
    int e = blockIdx.x * 256 + threadIdx.x;
    if (e >= EE) return;
    int src = ei[e];
    int dst = ei[EE + e];
    int g = batch[src];
    const float* L = lat + g * 9;
    float t0 = eshift[e*3+0], t1 = eshift[e*3+1], t2 = eshift[e*3+2];
    float vx = pos[dst*3+0] - pos[src*3+0] + t0*L[0] + t1*L[3] + t2*L[6];
    float vy = pos[dst*3+1] - pos[src*3+1] + t0*L[1] + t1*L[4] + t2*L[7];
    float vz = pos[dst*3+2] - pos[src*3+2] + t0*L[2] + t1*L[5] + t2*L[8];
    float r = sqrtf(vx*vx + vy*vy + vz*vz);
    float u = 2.0f * (r * (1.0f/3.5f) - 1.0f);
    float cut;
    if (u > 0.0f) cut = 0.0f;
    else if (u < -2.0f) cut = 1.0f;
    else cut = 0.5f * (1.0f - __cosf(PI_F * u));
    float inv = 1.0f / fmaxf(r, 1e-12f);
    float sc = SQRT3 * cut * inv;
    float t = fminf(r * TAB_SCALE + 0.5f, 4095.0f);
    int slot = atomicAdd(&cursor[dst], 1);
    geo4[slot] = make_float4(cut, sc * vx, sc * vy, sc * vz);
    grs[slot]  = make_float2(t, __int_as_float(src));
}

// ================= fused node-centric edge kernels (1 wave = 1 dst node) =================
// layer 1: 64 outputs: lane = q*16+c, q=0:ms, q=1..3:mv{x,y,z}; 4-edge unroll
#define F1_EDGE(G, R, ACC) {                                        \
    int i0_ = (int)(R).x;                                           \
    int src_ = __float_as_int((R).y);                               \
    float w_ = tab1[(size_t)i0_ * 32 + toff];                       \
    float xs_ = x[src_ * 16 + c];                                   \
    float gs_ = (q == 0) ? (G).x : (q == 1 ? (G).y : (q == 2 ? (G).z : (G).w)); \
    ACC += w_ * xs_ * gs_; }

__global__ __launch_bounds__(256) void k_fuse1(
    const int* __restrict__ rowp, const float4* __restrict__ geo4,
    const float2* __restrict__ grs, const float* __restrict__ tab1,
    const float* __restrict__ x, float* __restrict__ a1)
{
    int wid = (blockIdx.x * 256 + threadIdx.x) >> 6;
    int l = threadIdx.x & 63;
    if (wid >= NN) return;
    int b0 = __builtin_amdgcn_readfirstlane(rowp[wid]);
    int b1 = __builtin_amdgcn_readfirstlane(rowp[wid + 1]);
    int q = l >> 4, c = l & 15;
    int toff = (q ? 16 : 0) + c;
    float aA = 0.0f, aB = 0.0f, aC = 0.0f, aD = 0.0f;
    int s = b0;
    for (; s + 3 < b1; s += 4) {
        float4 gA = geo4[s], gB = geo4[s+1], gC = geo4[s+2], gD = geo4[s+3];
        float2 rA = grs[s],  rB = grs[s+1],  rC = grs[s+2],  rD = grs[s+3];
        F1_EDGE(gA, rA, aA) F1_EDGE(gB, rB, aB)
        F1_EDGE(gC, rC, aC) F1_EDGE(gD, rD, aD)
    }
    for (; s < b1; ++s) {
        float4 gA = geo4[s]; float2 rA = grs[s];
        F1_EDGE(gA, rA, aA)
    }
    a1[(size_t)wid * 64 + l] = (aA + aB) + (aC + aD);
}

// layer 2: parity halves own even/odd edges; every lane computes all 4 messages
// for channel c of ITS OWN edge. Cross-half fold at the end.
#define F2_EDGE(G, R, AS, AX, AY, AZ) {                             \
    int i0_ = (int)(R).x;                                           \
    int src_ = __float_as_int((R).y);                               \
    const float* T_ = tab2 + (size_t)i0_ * 160;                     \
    float w1_ = T_[c], w2_ = T_[32 + c], w3_ = T_[64 + c];          \
    float w4_ = T_[96 + c], w5_ = T_[128 + c];                      \
    float sv_ = s1[src_ * 32 + c];                                  \
    const unsigned short* vp_ = v1b + (size_t)src_ * 96;            \
    float vx_ = bf2f(vp_[c]), vy_ = bf2f(vp_[32 + c]), vz_ = bf2f(vp_[64 + c]); \
    float cs_ = (G).x, cx_ = (G).y, cy_ = (G).z, cz_ = (G).w;       \
    float dot_ = vx_ * cx_ + vy_ * cy_ + vz_ * cz_;                 \
    float w3s_ = w3_ * sv_, w4c_ = w4_ * cs_;                       \
    AS += w1_ * sv_ * cs_ + w2_ * dot_;                             \
    AX += w3s_ * cx_ + w4c_ * vx_ + w5_ * (vy_ * cz_ - vz_ * cy_);  \
    AY += w3s_ * cy_ + w4c_ * vy_ + w5_ * (vz_ * cx_ - vx_ * cz_);  \
    AZ += w3s_ * cz_ + w4c_ * vz_ + w5_ * (vx_ * cy_ - vy_ * cx_); }

__global__ __launch_bounds__(256) void k_fuse2(
    const int* __restrict__ rowp, const float4* __restrict__ geo4,
    const float2* __restrict__ grs, const float* __restrict__ tab2,
    const float* __restrict__ s1, const unsigned short* __restrict__ v1b,
    float* __restrict__ a2)
{
    int wid = (blockIdx.x * 256 + threadIdx.x) >> 6;
    int l = threadIdx.x & 63;
    if (wid >= NN) return;
    int b0 = __builtin_amdgcn_readfirstlane(rowp[wid]);
    int b1 = __builtin_amdgcn_readfirstlane(rowp[wid + 1]);
    int p = l >> 5, c = l & 31;
    float sA = 0, xA = 0, yA = 0, zA = 0;
    float sB = 0, xB = 0, yB = 0, zB = 0;
    int s = b0 + p;
    for (; s + 2 < b1; s += 4) {
        float4 gA = geo4[s], gB = geo4[s+2];
        float2 rA = grs[s],  rB = grs[s+2];
        F2_EDGE(gA, rA, sA, xA, yA, zA)
        F2_EDGE(gB, rB, sB, xB, yB, zB)
    }
    for (; s < b1; s += 2) {
        float4 gA = geo4[s]; float2 rA = grs[s];
        F2_EDGE(gA, rA, sA, xA, yA, zA)
    }
    float mS = sA + sB, mX = xA + xB, mY = yA + yB, mZ = zA + zB;
    mS += __shfl_xor(mS, 32);
    mX += __shfl_xor(mX, 32);
    mY += __shfl_xor(mY, 32);
    mZ += __shfl_xor(mZ, 32);
    if (p == 0) {
        float* ap = a2 + (size_t)wid * 128;
        ap[c]      = mS;
        ap[32 + c] = mX;
        ap[64 + c] = mY;
        ap[96 + c] = mZ;
    }
}

// output layer: lane = p*32+c; halves process even/odd slots; 2-edge unroll per half
#define F3_EDGE(G, R, ACC) {                                        \
    int i0_ = (int)(R).x;                                           \
    int src_ = __float_as_int((R).y);                               \
    const float* T_ = tab3 + (size_t)i0_ * 64;                      \
    float w1_ = T_[c], w2_ = T_[32 + c];                            \
    float sv_ = s2[src_ * 32 + c];                                  \
    const unsigned short* vp_ = v2b + (size_t)src_ * 96;            \
    float dot_ = bf2f(vp_[c]) * (G).y + bf2f(vp_[32 + c]) * (G).z + bf2f(vp_[64 + c]) * (G).w; \
    ACC += w1_ * sv_ * (G).x + w2_ * dot_; }

__global__ __launch_bounds__(256) void k_fuse3(
    const int* __restrict__ rowp, const float4* __restrict__ geo4,
    const float2* __restrict__ grs, const float* __restrict__ tab3,
    const float* __restrict__ s2, const unsigned short* __restrict__ v2b,
    float* __restrict__ a3)
{
    int wid = (blockIdx.x * 256 + threadIdx.x) >> 6;
    int l = threadIdx.x & 63;
    if (wid >= NN) return;
    int b0 = __builtin_amdgcn_readfirstlane(rowp[wid]);
    int b1 = __builtin_amdgcn_readfirstlane(rowp[wid + 1]);
    int p = l >> 5, c = l & 31;
    float aA = 0.0f, aB = 0.0f;
    int s = b0 + p;
    for (; s + 2 < b1; s += 4) {
        float4 gA = geo4[s], gB = geo4[s+2];
        float2 rA = grs[s],  rB = grs[s+2];
        F3_EDGE(gA, rA, aA)
        F3_EDGE(gB, rB, aB)
    }
    for (; s < b1; s += 2) {
        float4 gA = geo4[s]; float2 rA = grs[s];
        F3_EDGE(gA, rA, aA)
    }
    float acc = aA + aB;
    acc += __shfl_xor(acc, 32);
    if (p == 0) a3[(size_t)wid * 32 + c] = acc;
}

// ================= node kernels =================
// a1 layout per node (64 floats): [ms 16][mvx 16][mvy 16][mvz 16]
__global__ __launch_bounds__(256) void k_node1(
    const float* __restrict__ x, const float* __restrict__ z,
    const float* __restrict__ a1,
    const float* __restrict__ sc1, const float* __restrict__ lin1s,
    const float* __restrict__ lin1v,
    float* __restrict__ s1, float* __restrict__ v1,
    unsigned short* __restrict__ v1b)
{
    int n = blockIdx.x * 256 + threadIdx.x;
    if (n >= NN) return;
    float zz = z[n];
    float xs[16], as[16];
#pragma unroll
    for (int c = 0; c < 16; ++c) {
        xs[c] = x[n * 16 + c] * zz;
        as[c] = a1[n * 64 + c] * INV_SQRT_NEIGH;
    }
    float sh[64];
#pragma unroll
    for (int o = 0; o < 64; ++o) sh[o] = 0.0f;
    for (int c = 0; c < 16; ++c) {
        float xc = xs[c], ac = as[c];
#pragma unroll
        for (int o = 0; o < 64; ++o)
            sh[o] += xc * sc1[c * 64 + o] + ac * lin1s[c * 64 + o];
    }
    float gate[32];
#pragma unroll
    for (int o = 0; o < 32; ++o) {
        s1[n * 32 + o] = silu_f(sh[o]);
        gate[o] = sigm_f(sh[32 + o]);
    }
    for (int i = 0; i < 3; ++i) {
        float av[16];
#pragma unroll
        for (int c = 0; c < 16; ++c) av[c] = a1[n * 64 + 16 + i * 16 + c] * INV_SQRT_NEIGH;
        float vh[32];
#pragma unroll
        for (int o = 0; o < 32; ++o) vh[o] = 0.0f;
        for (int c = 0; c < 16; ++c) {
            float ac = av[c];
#pragma unroll
            for (int o = 0; o < 32; ++o) vh[o] += ac * lin1v[c * 32 + o];
        }
#pragma unroll
        for (int o = 0; o < 32; ++o) {
            float v = vh[o] * gate[o];
            v1[(n * 3 + i) * 32 + o] = v;
            v1b[(size_t)(n * 3 + i) * 32 + o] = f2bf(v);
        }
    }
}

// a2 layout per node (128 floats): [ms 32][mvx 32][mvy 32][mvz 32]
__global__ __launch_bounds__(256) void k_node2(
    const float* __restrict__ z,
    const float* __restrict__ s1, const float* __restrict__ v1,
    const float* __restrict__ a2,
    const float* __restrict__ sc2s, const float* __restrict__ sc2v,
    const float* __restrict__ lin2s, const float* __restrict__ lin2v,
    float* __restrict__ s2, unsigned short* __restrict__ v2b)
{
    int n = blockIdx.x * 256 + threadIdx.x;
    if (n >= NN) return;
    float zz = z[n];
    float sv[32], as[32];
#pragma unroll
    for (int c = 0; c < 32; ++c) {
        sv[c] = s1[n * 32 + c] * zz;
        as[c] = a2[(size_t)n * 128 + c] * INV_SQRT_NEIGH;
    }
    float sh[64];
#pragma unroll
    for (int o = 0; o < 64; ++o) sh[o] = 0.0f;
    for (int c = 0; c < 32; ++c) {
        float a = sv[c], d = as[c];
#pragma unroll
        for (int o = 0; o < 64; ++o)
            sh[o] += a * sc2s[c * 64 + o] + d * lin2s[c * 64 + o];
    }
    float gate[32];
#pragma unroll
    for (int o = 0; o < 32; ++o) {
        s2[n * 32 + o] = silu_f(sh[o]);
        gate[o] = sigm_f(sh[32 + o]);
    }
    for (int i = 0; i < 3; ++i) {
        float vv[32], av[32];
#pragma unroll
        for (int c = 0; c < 32; ++c) {
            vv[c] = v1[(n * 3 + i) * 32 + c];
            av[c] = a2[(size_t)n * 128 + 32 + i * 32 + c] * INV_SQRT_NEIGH;
        }
        float vh[32];
#pragma unroll
        for (int o = 0; o < 32; ++o) vh[o] = 0.0f;
        for (int c = 0; c < 32; ++c) {
            float a = vv[c], d = av[c];
#pragma unroll
            for (int o = 0; o < 32; ++o)
                vh[o] += a * sc2v[c * 32 + o] + d * lin2v[c * 32 + o];
        }
#pragma unroll
        for (int o = 0; o < 32; ++o)
            v2b[(size_t)(n * 3 + i) * 32 + o] = f2bf(vh[o] * gate[o]);
    }
}

// ---- output stage 1: per-(graph,split) partial sums of [s2*z | a3] ----
__global__ __launch_bounds__(256) void k_red(
    const float* __restrict__ z, const int* __restrict__ gstart,
    const float* __restrict__ s2, const float* __restrict__ a3,
    float* __restrict__ pbuf)
{
    int g  = blockIdx.x >> 4;      // / SPL
    int sp = blockIdx.x & (SPL - 1);
    int n0 = gstart[g], n1 = gstart[g + 1];
    int per = (n1 - n0 + SPL - 1) / SPL;
    int a = n0 + sp * per;
    int b = a + per; if (b > n1) b = n1;
    int t = threadIdx.x;
    int comp = t & 63;
    int lane = t >> 6;
    float acc = 0.0f;
    for (int n = a + lane; n < b; n += 4) {
        if (comp < 32) acc += s2[n * 32 + comp] * z[n];
        else           acc += a3[(size_t)n * 32 + (comp - 32)];
    }
    __shared__ float sd[256];
    sd[t] = acc;
    __syncthreads();
    if (t < 64)
        pbuf[(size_t)blockIdx.x * 64 + t] = sd[t] + sd[t + 64] + sd[t + 128] + sd[t + 192];
}

// ---- output stage 2: fold partials + (64,32)@(32,100) GEMM ----
__global__ __launch_bounds__(128) void k_out2(
    const float* __restrict__ pbuf, const float* __restrict__ sco,
    const float* __restrict__ lino, float* __restrict__ out)
{
    __shared__ float A[32], B[32];
    int g = blockIdx.x;
    int t = threadIdx.x;
    if (t < 64) {
        float v = 0.0f;
        for (int sp = 0; sp < SPL; ++sp)
            v += pbuf[(size_t)(g * SPL + sp) * 64 + t];
        if (t < 32) A[t] = v;
        else        B[t - 32] = v * INV_SQRT_NEIGH;
    }
    __syncthreads();
    if (t < 100) {
        float res = 0.0f;
#pragma unroll
        for (int c = 0; c < 32; ++c)
            res += A[c] * sco[c * 100 + t] + B[c] * lino[c * 100 + t];
        out[g * 100 + t] = res * INV_SQRT_NODES;
    }
}

// ================= launcher =================
extern "C" void kernel_launch(void* const* d_in, const int* in_sizes, int n_in,
                              void* d_out, int out_size, void* d_ws, size_t ws_size,
                              hipStream_t stream)
{
    const float* pos   = (const float*)d_in[0];
    const float* x     = (const float*)d_in[1];
    const float* z     = (const float*)d_in[2];
    const int*   ei    = (const int*)d_in[3];
    const float* esh   = (const float*)d_in[4];
    const float* lat   = (const float*)d_in[5];
    const int*   batch = (const int*)d_in[6];
    const float* fc1w0 = (const float*)d_in[7];
    const float* fc1w1 = (const float*)d_in[8];
    const float* sc1   = (const float*)d_in[9];
    const float* lin1s = (const float*)d_in[10];
    const float* lin1v = (const float*)d_in[11];
    const float* fc2w0 = (const float*)d_in[12];
    const float* fc2w1 = (const float*)d_in[13];
    const float* sc2s  = (const float*)d_in[14];
    const float* sc2v  = (const float*)d_in[15];
    const float* lin2s = (const float*)d_in[16];
    const float* lin2v = (const float*)d_in[17];
    const float* fcow0 = (const float*)d_in[18];
    const float* fcow1 = (const float*)d_in[19];
    const float* sco   = (const float*)d_in[20];
    const float* lino  = (const float*)d_in[21];
    float* out = (float*)d_out;

    char* cur = (char*)d_ws;
    auto alloc = [&](size_t bytes) { char* r = cur; cur += (bytes + 15) & ~(size_t)15; return r; };

    float* a1   = (float*)alloc((size_t)NN * 64 * 4);
    float* a2   = (float*)alloc((size_t)NN * 128 * 4);
    float* a3   = (float*)alloc((size_t)NN * 32 * 4);
    float* s1   = (float*)alloc((size_t)NN * 32 * 4);
    float* v1   = (float*)alloc((size_t)NN * 96 * 4);
    float* s2   = (float*)alloc((size_t)NN * 32 * 4);
    unsigned short* v1b = (unsigned short*)alloc((size_t)NN * 96 * 2);
    unsigned short* v2b = (unsigned short*)alloc((size_t)NN * 96 * 2);
    float* tab1 = (float*)alloc((size_t)NTAB * 32 * 4);
    float* tab2 = (float*)alloc((size_t)NTAB * 160 * 4);
    float* tab3 = (float*)alloc((size_t)NTAB * 64 * 4);
    float* pbuf = (float*)alloc((size_t)NGRAPHS * SPL * 64 * 4);
    int* deg    = (int*)alloc((size_t)NN * 4);
    int* rowp   = (int*)alloc((size_t)(NN + 4) * 4);
    int* cursor = (int*)alloc((size_t)NN * 4);
    int* bsum   = (int*)alloc(256 * 4);
    int* boff   = (int*)alloc(256 * 4);
    int* gstart = (int*)alloc(68 * 4);
    float4* geo4 = (float4*)alloc((size_t)EE * 16);
    float2* grs  = (float2*)alloc((size_t)EE * 8);

    (void)hipMemsetAsync(deg, 0, (size_t)NN * 4, stream);

    // tables + graph bounds + degree histogram in one dispatch
    k_pre<<<256 + NB_N + NB_E, 256, 0, stream>>>(
        fc1w0, fc1w1, fc2w0, fc2w1, fcow0, fcow1, tab1, tab2, tab3,
        batch, gstart, ei, deg);

    k_scan1<<<NB_N, 256, 0, stream>>>(deg, bsum);
    k_scan2<<<1, 64, 0, stream>>>(bsum, boff, rowp);
    k_scan3<<<NB_N, 256, 0, stream>>>(deg, boff, rowp, cursor);
    k_geom <<<NB_E, 256, 0, stream>>>(pos, ei, esh, lat, batch, cursor, geo4, grs);

    int fb = (NN * 64 + 255) / 256;   // 1 wave per node
    k_fuse1<<<fb, 256, 0, stream>>>(rowp, geo4, grs, tab1, x, a1);
    k_node1<<<NB_N, 256, 0, stream>>>(x, z, a1, sc1, lin1s, lin1v, s1, v1, v1b);
    k_fuse2<<<fb, 256, 0, stream>>>(rowp, geo4, grs, tab2, s1, v1b, a2);
    k_node2<<<NB_N, 256, 0, stream>>>(z, s1, v1, a2, sc2s, sc2v, lin2s, lin2v, s2, v2b);
    k_fuse3<<<fb, 256, 0, stream>>>(rowp, geo4, grs, tab3, s2, v2b, a3);
    k_red<<<NGRAPHS * SPL, 256, 0, stream>>>(z, gstart, s2, a3, pbuf);
    k_out2<<<NGRAPHS, 128, 0, stream>>>(pbuf, sco, lino, out);
}